// Round 1
// baseline (7782.912 us; speedup 1.0000x reference)
//
#include <hip/hip_runtime.h>

#define NROWS 8192
#define NG    12972
#define H     1000
#define HP    1008   // padded K for hidden layers (63*16)
#define KX    288    // padded hints width (18*16)
#define OC    130
#define EPSBN 1e-5f

__device__ __forceinline__ float lrelu(float x) { return x >= 0.f ? x : 0.2f * x; }

// ---------------- prep ----------------
__global__ void prep_weights(const float* __restrict__ W0, const float* __restrict__ Wh,
                             float* __restrict__ W0p, float* __restrict__ Whp) {
    int i = blockIdx.x * blockDim.x + threadIdx.x;
    if (i < KX * H) {
        int r = i / H, c = i - r * H;
        W0p[i] = (r < 286) ? W0[r * H + c] : 0.f;
    } else {
        int j = i - KX * H;
        if (j < 3 * HP * H) {
            int l = j / (HP * H);
            int rem = j - l * (HP * H);
            int r = rem / H, c = rem - r * H;
            Whp[j] = (r < H) ? Wh[(size_t)(l * H + r) * H + c] : 0.f;
        }
    }
}

__global__ void prep_guess_letters(const float* __restrict__ gm, unsigned char* __restrict__ gl) {
    int g = blockIdx.x * blockDim.x + threadIdx.x;
    if (g >= NG) return;
    for (int p = 0; p < 5; ++p) {
        int letter = 0;
        for (int c = 0; c < 26; ++c)
            if (gm[(size_t)g * 130 + c * 5 + p] > 0.5f) { letter = c; break; }
        gl[g * 8 + p] = (unsigned char)letter;
    }
    gl[g * 8 + 5] = gl[g * 8 + 6] = gl[g * 8 + 7] = 0;
}

__global__ void prep_sol_letters(const float* __restrict__ sols, unsigned char* __restrict__ sl,
                                 unsigned int* __restrict__ msk) {
    int r = blockIdx.x * blockDim.x + threadIdx.x;
    if (r >= NROWS) return;
    unsigned int m = 0;
    for (int p = 0; p < 5; ++p) {
        int letter = 0;
        for (int c = 0; c < 26; ++c)
            if (sols[(size_t)r * 130 + c * 5 + p] > 0.5f) { letter = c; break; }
        sl[r * 8 + p] = (unsigned char)letter;
        m |= 1u << letter;
    }
    sl[r * 8 + 5] = sl[r * 8 + 6] = sl[r * 8 + 7] = 0;
    msk[r] = m;
}

__global__ void init_state(float* __restrict__ hintsX, float* __restrict__ scores,
                           int* __restrict__ solvedf, float* __restrict__ lossacc) {
    int i = blockIdx.x * blockDim.x + threadIdx.x;
    if (i < NROWS * KX) hintsX[i] = 0.f;
    if (i < NROWS) { scores[i] = 7.f; solvedf[i] = 0; }
    if (i == 0) lossacc[0] = 0.f;
}

// ---------------- GEMM (fp32, 64x64 tile, BK=16, 4x4 micro) ----------------
__global__ __launch_bounds__(256) void gemm_f32(
    const float* __restrict__ A, int lda,
    const float* __restrict__ B, int ldb, int brows, int ncols,
    float* __restrict__ C, int ldc, int kiter,
    const float* __restrict__ bias1, const float* __restrict__ bias2) {
    __shared__ __align__(16) float As[16][68];  // [k][row], row-stride 272B (16B aligned)
    __shared__ __align__(16) float Bs[16][68];  // [k][col]
    const int tid = threadIdx.x;
    const int rowBase = blockIdx.x * 64, colBase = blockIdx.y * 64;
    const int tm = tid >> 4, tn = tid & 15;
    const int ak = tid & 15, ar = tid >> 4;
    const int bcol = tid & 63, bk0 = tid >> 6;

    float acc[4][4] = {};
    for (int t = 0; t < kiter; ++t) {
        const int k0 = t * 16;
#pragma unroll
        for (int pass = 0; pass < 4; ++pass) {
            int row = ar + pass * 16;
            As[ak][row] = A[(size_t)(rowBase + row) * lda + k0 + ak];
            int kk = bk0 + pass * 4;
            int gcol = colBase + bcol;
            float bv = 0.f;
            if (k0 + kk < brows && gcol < ncols) bv = B[(size_t)(k0 + kk) * ldb + gcol];
            Bs[kk][bcol] = bv;
        }
        __syncthreads();
#pragma unroll
        for (int kk = 0; kk < 16; ++kk) {
            const float4 af = *(const float4*)&As[kk][tm * 4];
            const float4 bf = *(const float4*)&Bs[kk][tn * 4];
            const float aa[4] = {af.x, af.y, af.z, af.w};
            const float bb[4] = {bf.x, bf.y, bf.z, bf.w};
#pragma unroll
            for (int i = 0; i < 4; ++i)
#pragma unroll
                for (int j = 0; j < 4; ++j) acc[i][j] = fmaf(aa[i], bb[j], acc[i][j]);
        }
        __syncthreads();
    }
    // epilogue: + bias1 (+ bias2)
    const int col0 = colBase + tn * 4;
    float bias[4];
#pragma unroll
    for (int j = 0; j < 4; ++j) {
        int col = col0 + j;
        bias[j] = (col < ncols) ? (bias1[col] + (bias2 ? bias2[col] : 0.f)) : 0.f;
    }
    const bool v4 = ((ldc & 3) == 0) && (col0 + 3 < ncols);
#pragma unroll
    for (int i = 0; i < 4; ++i) {
        int row = rowBase + tm * 4 + i;
        if (v4) {
            float4 o;
            o.x = acc[i][0] + bias[0]; o.y = acc[i][1] + bias[1];
            o.z = acc[i][2] + bias[2]; o.w = acc[i][3] + bias[3];
            *(float4*)&C[(size_t)row * ldc + col0] = o;
        } else {
#pragma unroll
            for (int j = 0; j < 4; ++j)
                if (col0 + j < ncols) C[(size_t)row * ldc + col0 + j] = acc[i][j] + bias[j];
        }
    }
}

// ---------------- BatchNorm ----------------
__global__ void bn_partial(const float* __restrict__ h, float* __restrict__ pS, float* __restrict__ pS2) {
    int col = blockIdx.x * 256 + threadIdx.x;
    int chunk = blockIdx.y;
    if (col >= H) return;
    const float* p = h + (size_t)chunk * 256 * H + col;
    float s = 0.f, s2 = 0.f;
    for (int r = 0; r < 256; ++r) {
        float v = p[(size_t)r * H];
        s += v; s2 += v * v;
    }
    pS[chunk * H + col] = s;
    pS2[chunk * H + col] = s2;
}

__global__ void bn_final(const float* __restrict__ pS, const float* __restrict__ pS2,
                         const float* __restrict__ gamma, const float* __restrict__ beta,
                         float* __restrict__ bnA, float* __restrict__ bnB) {
    int c = blockIdx.x * 256 + threadIdx.x;
    if (c >= H) return;
    float s = 0.f, s2 = 0.f;
    for (int j = 0; j < 32; ++j) { s += pS[j * H + c]; s2 += pS2[j * H + c]; }
    float mean = s * (1.f / NROWS);
    float var = s2 * (1.f / NROWS) - mean * mean;
    float inv = rsqrtf(var + EPSBN);
    float a = gamma[c] * inv;
    bnA[c] = a;
    bnB[c] = beta[c] - mean * a;
}

__global__ void bn_apply(const float* __restrict__ h, const float* __restrict__ bnA,
                         const float* __restrict__ bnB, float* __restrict__ hA) {
    int i = blockIdx.x * 256 + threadIdx.x;
    if (i >= NROWS * HP) return;
    int r = i / HP, c = i - r * HP;
    float v = 0.f;
    if (c < H) v = lrelu(bnA[c] * h[(size_t)r * H + c] + bnB[c]);
    hA[i] = v;
}

// ---------------- softmax + loss ----------------
__global__ __launch_bounds__(256) void softmax_loss(
    const float* __restrict__ y, float* __restrict__ ysoft,
    const unsigned char* __restrict__ sl, float* __restrict__ lossacc, int addloss) {
    int i = blockIdx.x * 256 + threadIdx.x;  // 40960 threads = N*5
    int r = i / 5, p = i - r * 5;
    const float* yr = y + (size_t)r * OC + p;
    float m = -1e30f;
#pragma unroll
    for (int c = 0; c < 26; ++c) m = fmaxf(m, yr[c * 5]);
    float e[26];
    float s = 0.f;
#pragma unroll
    for (int c = 0; c < 26; ++c) { e[c] = expf(yr[c * 5] - m); s += e[c]; }
    float inv = 1.f / s;
#pragma unroll
    for (int c = 0; c < 26; ++c) ysoft[(size_t)r * OC + c * 5 + p] = e[c] * inv;
    float contrib = 0.f;
    if (addloss) {
        int letter = sl[r * 8 + p];
        contrib = logf(s) + m - yr[letter * 5];  // = -logp[sol letter]
    }
    __shared__ float red[256];
    red[threadIdx.x] = contrib;
    __syncthreads();
    for (int off = 128; off > 0; off >>= 1) {
        if (threadIdx.x < off) red[threadIdx.x] += red[threadIdx.x + off];
        __syncthreads();
    }
    if (threadIdx.x == 0 && addloss) atomicAdd(lossacc, red[0] * (1.f / (NROWS * 5)));
}

// ---------------- argmax over vocabulary ----------------
__global__ __launch_bounds__(64) void argmax_kernel(const float* __restrict__ ysoft,
                                                    const unsigned char* __restrict__ gl,
                                                    int* __restrict__ idxbuf) {
    int r = blockIdx.x;
    __shared__ float row[OC];
    int tid = threadIdx.x;
    for (int j = tid; j < OC; j += 64) row[j] = ysoft[(size_t)r * OC + j];
    __syncthreads();
    float best = -1e30f;
    int bi = NG;
    for (int g = tid; g < NG; g += 64) {
        const unsigned char* q = gl + g * 8;
        float s = row[q[0] * 5 + 0] + row[q[1] * 5 + 1] + row[q[2] * 5 + 2] +
                  row[q[3] * 5 + 3] + row[q[4] * 5 + 4];
        if (s > best) { best = s; bi = g; }  // strict > keeps first max within lane
    }
    for (int off = 32; off > 0; off >>= 1) {
        float ob = __shfl_down(best, off);
        int oi = __shfl_down(bi, off);
        if (ob > best || (ob == best && oi < bi)) { best = ob; bi = oi; }
    }
    if (tid == 0) idxbuf[r] = bi;
}

// ---------------- hint update / scores ----------------
__global__ void hints_update(const int* __restrict__ idxbuf, const unsigned char* __restrict__ gl,
                             const unsigned char* __restrict__ sl, const unsigned int* __restrict__ msk,
                             float* __restrict__ hintsX, float* __restrict__ scores,
                             int* __restrict__ solvedf, const float* __restrict__ gm,
                             float* __restrict__ dout, int turn) {
    int r = blockIdx.x * 256 + threadIdx.x;
    if (r >= NROWS) return;
    int w = idxbuf[r];
    const unsigned char* q = gl + w * 8;
    const unsigned char* s = sl + r * 8;
    unsigned int mk = msk[r];
    float* hrow = hintsX + (size_t)r * KX;
    int allg = 1;
#pragma unroll
    for (int p = 0; p < 5; ++p) {
        int g = q[p];
        if (g == s[p]) {
            hrow[g * 5 + p] += 1.f;            // green
        } else {
            allg = 0;
            if ((mk >> g) & 1u) hrow[130 + g * 5 + p] += 1.f;  // yellow
            else hrow[260 + g] += 1.f;                          // black
        }
    }
    solvedf[r] = allg;
    if (allg && scores[r] > (float)(turn + 1)) scores[r] = (float)(turn + 1);
    if (turn == 0 && r == 0) {
        for (int j = 0; j < OC; ++j) dout[3 + j] = gm[(size_t)w * OC + j];
    }
}

__global__ void final_reduce(const float* __restrict__ scores, const int* __restrict__ solvedf,
                             const float* __restrict__ lossacc, float* __restrict__ dout) {
    __shared__ float rs[256];
    __shared__ int ri[256];
    int tid = threadIdx.x;
    float s = 0.f;
    int c = 0;
    for (int r = tid; r < NROWS; r += 256) { s += scores[r]; c += solvedf[r]; }
    rs[tid] = s; ri[tid] = c;
    __syncthreads();
    for (int off = 128; off > 0; off >>= 1) {
        if (tid < off) { rs[tid] += rs[tid + off]; ri[tid] += ri[tid + off]; }
        __syncthreads();
    }
    if (tid == 0) {
        dout[0] = lossacc[0];
        dout[1] = rs[0];
        dout[2] = (float)ri[0];
    }
}

// ---------------- launch ----------------
extern "C" void kernel_launch(void* const* d_in, const int* in_sizes, int n_in,
                              void* d_out, int out_size, void* d_ws, size_t ws_size,
                              hipStream_t stream) {
    const float* sols   = (const float*)d_in[0];
    const float* gm     = (const float*)d_in[1];
    const float* W0     = (const float*)d_in[2];
    const float* b0     = (const float*)d_in[3];
    const float* gammas = (const float*)d_in[4];
    const float* betas  = (const float*)d_in[5];
    const float* Wh     = (const float*)d_in[6];
    const float* bh     = (const float*)d_in[7];
    const float* Wout   = (const float*)d_in[8];
    const float* bout   = (const float*)d_in[9];
    float* dout = (float*)d_out;

    char* p = (char*)d_ws;
    auto alloc = [&](size_t bytes) { void* r = (void*)p; p += (bytes + 255) & ~(size_t)255; return r; };
    float* hintsX = (float*)alloc((size_t)NROWS * KX * 4);
    float* hraw   = (float*)alloc((size_t)NROWS * H * 4);
    float* hA     = (float*)alloc((size_t)NROWS * HP * 4);
    float* ybuf   = (float*)alloc((size_t)NROWS * OC * 4);
    float* ysoft  = (float*)alloc((size_t)NROWS * OC * 4);
    float* W0p    = (float*)alloc((size_t)KX * H * 4);
    float* Whp    = (float*)alloc((size_t)3 * HP * H * 4);
    float* pS     = (float*)alloc((size_t)32 * H * 4);
    float* pS2    = (float*)alloc((size_t)32 * H * 4);
    float* bnA    = (float*)alloc(H * 4);
    float* bnB    = (float*)alloc(H * 4);
    float* scores = (float*)alloc(NROWS * 4);
    float* lossacc = (float*)alloc(256);
    int* solvedf  = (int*)alloc(NROWS * 4);
    int* idxbuf   = (int*)alloc(NROWS * 4);
    unsigned char* gl = (unsigned char*)alloc(NG * 8);
    unsigned char* sl = (unsigned char*)alloc(NROWS * 8);
    unsigned int* msk = (unsigned int*)alloc(NROWS * 4);

    // prep
    {
        int total = KX * H + 3 * HP * H;
        prep_weights<<<(total + 255) / 256, 256, 0, stream>>>(W0, Wh, W0p, Whp);
        prep_guess_letters<<<(NG + 255) / 256, 256, 0, stream>>>(gm, gl);
        prep_sol_letters<<<(NROWS + 255) / 256, 256, 0, stream>>>(sols, sl, msk);
        init_state<<<(NROWS * KX + 255) / 256, 256, 0, stream>>>(hintsX, scores, solvedf, lossacc);
    }

    for (int t = 0; t < 6; ++t) {
        // h = X @ W0 + b0   (turn-vec columns folded into bias)
        gemm_f32<<<dim3(NROWS / 64, 16), 256, 0, stream>>>(
            hintsX, KX, W0p, H, KX, H, hraw, H, KX / 16, b0, W0 + (size_t)(286 + t) * H);
        for (int l = 0; l < 4; ++l) {
            bn_partial<<<dim3(4, 32), 256, 0, stream>>>(hraw, pS, pS2);
            bn_final<<<4, 256, 0, stream>>>(pS, pS2, gammas + (size_t)l * H, betas + (size_t)l * H, bnA, bnB);
            bn_apply<<<(NROWS * HP + 255) / 256, 256, 0, stream>>>(hraw, bnA, bnB, hA);
            if (l < 3) {
                gemm_f32<<<dim3(NROWS / 64, 16), 256, 0, stream>>>(
                    hA, HP, Whp + (size_t)l * HP * H, H, HP, H, hraw, H, HP / 16,
                    bh + (size_t)l * H, nullptr);
            } else {
                gemm_f32<<<dim3(NROWS / 64, 3), 256, 0, stream>>>(
                    hA, HP, Wout, OC, H, OC, ybuf, OC, HP / 16, bout, nullptr);
            }
        }
        softmax_loss<<<(NROWS * 5) / 256, 256, 0, stream>>>(ybuf, ysoft, sl, lossacc, (t >= 1) ? 1 : 0);
        argmax_kernel<<<NROWS, 64, 0, stream>>>(ysoft, gl, idxbuf);
        hints_update<<<(NROWS + 255) / 256, 256, 0, stream>>>(idxbuf, gl, sl, msk, hintsX, scores,
                                                              solvedf, gm, dout, t);
    }
    final_reduce<<<1, 256, 0, stream>>>(scores, solvedf, lossacc, dout);
}

// Round 2
// 3120.166 us; speedup vs baseline: 2.4944x; 2.4944x over previous
//
#include <hip/hip_runtime.h>

#define NROWS 8192
#define NG    12972
#define H     1000
#define NP    1024   // padded hidden width
#define KX    288    // padded hints width (multiple of 32)
#define OCP   256    // padded output cols
#define OC    130
#define EPSBN 1e-5f

typedef __attribute__((ext_vector_type(8))) short bf16x8;
typedef __attribute__((ext_vector_type(4))) float f32x4;

__device__ __forceinline__ float lrelu(float x) { return x >= 0.f ? x : 0.2f * x; }
__device__ __forceinline__ unsigned short f2bf(float f) {
    unsigned u = __float_as_uint(f);
    return (unsigned short)((u + 0x7fffu + ((u >> 16) & 1u)) >> 16);
}
__device__ __forceinline__ float bf2f(unsigned short h) {
    return __uint_as_float(((unsigned)h) << 16);
}

// ---------------- prep: transpose + split fp32 -> bf16 hi/lo, B^T layout ----------------
// dst[n][k] = src[k][n] for k<R, n<C, else 0. dst dims [Cp][Rp].
__global__ void transpose_split(const float* __restrict__ src, int R, int C, int srcStride,
                                unsigned short* __restrict__ dhi, unsigned short* __restrict__ dlo,
                                int Rp, int Cp) {
    __shared__ float tile[32][33];
    int k0 = blockIdx.x * 32;
    int n0 = blockIdx.y * 32;
    int tx = threadIdx.x, ty = threadIdx.y;  // 32 x 8
#pragma unroll
    for (int i = 0; i < 32; i += 8) {
        int k = k0 + ty + i, n = n0 + tx;
        tile[ty + i][tx] = (k < R && n < C) ? src[(size_t)k * srcStride + n] : 0.f;
    }
    __syncthreads();
#pragma unroll
    for (int i = 0; i < 32; i += 8) {
        int n = n0 + ty + i, k = k0 + tx;
        if (n < Cp && k < Rp) {
            float v = tile[tx][ty + i];
            unsigned short hi = f2bf(v);
            dhi[(size_t)n * Rp + k] = hi;
            dlo[(size_t)n * Rp + k] = f2bf(v - bf2f(hi));
        }
    }
}

__global__ void prep_bias(const float* __restrict__ W0, const float* __restrict__ b0,
                          const float* __restrict__ bh, const float* __restrict__ bout,
                          float* __restrict__ b0p, float* __restrict__ w0t,
                          float* __restrict__ bhp, float* __restrict__ boutp) {
    int i = blockIdx.x * 256 + threadIdx.x;
    if (i < 1024) { b0p[i] = (i < H) ? b0[i] : 0.f; return; }
    i -= 1024;
    if (i < 6 * 1024) {
        int t = i >> 10, n = i & 1023;
        w0t[i] = (n < H) ? W0[(size_t)(286 + t) * H + n] : 0.f;
        return;
    }
    i -= 6 * 1024;
    if (i < 3 * 1024) {
        int l = i >> 10, n = i & 1023;
        bhp[i] = (n < H) ? bh[l * H + n] : 0.f;
        return;
    }
    i -= 3 * 1024;
    if (i < OCP) { boutp[i] = (i < OC) ? bout[i] : 0.f; }
}

__global__ void prep_guess_letters(const float* __restrict__ gm, unsigned char* __restrict__ gl) {
    int g = blockIdx.x * blockDim.x + threadIdx.x;
    if (g >= NG) return;
    for (int p = 0; p < 5; ++p) {
        int letter = 0;
        for (int c = 0; c < 26; ++c)
            if (gm[(size_t)g * 130 + c * 5 + p] > 0.5f) { letter = c; break; }
        gl[g * 8 + p] = (unsigned char)letter;
    }
    gl[g * 8 + 5] = gl[g * 8 + 6] = gl[g * 8 + 7] = 0;
}

__global__ void prep_sol_letters(const float* __restrict__ sols, unsigned char* __restrict__ sl,
                                 unsigned int* __restrict__ msk) {
    int r = blockIdx.x * blockDim.x + threadIdx.x;
    if (r >= NROWS) return;
    unsigned int m = 0;
    for (int p = 0; p < 5; ++p) {
        int letter = 0;
        for (int c = 0; c < 26; ++c)
            if (sols[(size_t)r * 130 + c * 5 + p] > 0.5f) { letter = c; break; }
        sl[r * 8 + p] = (unsigned char)letter;
        m |= 1u << letter;
    }
    sl[r * 8 + 5] = sl[r * 8 + 6] = sl[r * 8 + 7] = 0;
    msk[r] = m;
}

__global__ void init_state(unsigned short* __restrict__ hXh, unsigned short* __restrict__ hXl,
                           float* __restrict__ scores, int* __restrict__ solvedf,
                           float* __restrict__ lossacc) {
    int i = blockIdx.x * blockDim.x + threadIdx.x;
    if (i < NROWS * KX) { hXh[i] = 0; hXl[i] = 0; }
    if (i < NROWS) { scores[i] = 7.f; solvedf[i] = 0; }
    if (i == 0) lossacc[0] = 0.f;
}

// ---------------- GEMM: C = Ah*Bh + Ah*Bl + Al*Bh (+bias), MFMA 16x16x32 bf16 ----------------
// A planes: [M][lda] bf16 row-major. B planes: B^T layout [Ncols][ldb] bf16 (8 contiguous k per frag).
// Block 128x128, 4 waves (2x2), wave tile 64x64, BK=32. LDS: Ah|Al|Bh|Bl each [4kb][128][8] bf16 = 8KB.
__global__ __launch_bounds__(256, 2) void gemm_bf16x2(
    const unsigned short* __restrict__ Ah, const unsigned short* __restrict__ Al, int lda,
    const unsigned short* __restrict__ Bh, const unsigned short* __restrict__ Bl, int ldb,
    float* __restrict__ C, int ldc,
    const float* __restrict__ bias1, const float* __restrict__ bias2, int kiter) {
    __shared__ char smem[32768];
    const int tid = threadIdx.x;
    const int lane = tid & 63;
    const int rowBase = blockIdx.x * 128;
    const int colBase = blockIdx.y * 128;
    const int wm = (tid >> 6) & 1;
    const int wn = tid >> 7;

    // staging map: chunk c = i*256+tid; tile=c>>9 (Ah,Al,Bh,Bl); w=c&511; kb=w>>7; r=w&127
    const unsigned short* gsrc[8];
    int ldsuni[8];
#pragma unroll
    for (int i = 0; i < 8; ++i) {
        int c = i * 256 + tid;
        int tile = c >> 9, w = c & 511, kb = w >> 7, r = w & 127;
        const unsigned short* plane = (tile == 0) ? Ah : (tile == 1) ? Al : (tile == 2) ? Bh : Bl;
        int ld = (tile < 2) ? lda : ldb;
        int base = (tile < 2) ? rowBase : colBase;
        gsrc[i] = plane + (size_t)(base + r) * ld + kb * 8;
        ldsuni[i] = (i * 256 + (tid & ~63)) * 16;  // wave-uniform byte base
    }

    f32x4 acc[4][4];
    const f32x4 z = {0.f, 0.f, 0.f, 0.f};
#pragma unroll
    for (int m = 0; m < 4; ++m)
#pragma unroll
        for (int n = 0; n < 4; ++n) acc[m][n] = z;

    const int aro = (lane >> 4) * 2048 + (wm * 64 + (lane & 15)) * 16;
    const int bco = (lane >> 4) * 2048 + (wn * 64 + (lane & 15)) * 16;

    for (int t = 0; t < kiter; ++t) {
#if __has_builtin(__builtin_amdgcn_global_load_lds)
#pragma unroll
        for (int i = 0; i < 8; ++i) {
            __builtin_amdgcn_global_load_lds(
                (const __attribute__((address_space(1))) void*)(gsrc[i] + t * 32),
                (__attribute__((address_space(3))) void*)(smem + ldsuni[i]), 16, 0, 0);
        }
        __syncthreads();
#else
        bf16x8 stg[8];
#pragma unroll
        for (int i = 0; i < 8; ++i) stg[i] = *(const bf16x8*)(gsrc[i] + t * 32);
        __syncthreads();
#pragma unroll
        for (int i = 0; i < 8; ++i) *(bf16x8*)(smem + (i * 256 + tid) * 16) = stg[i];
        __syncthreads();
#endif
        bf16x8 a_h[4], a_l[4], b_h[4], b_l[4];
#pragma unroll
        for (int m = 0; m < 4; ++m) {
            a_h[m] = *(const bf16x8*)(smem + aro + m * 256);
            a_l[m] = *(const bf16x8*)(smem + 8192 + aro + m * 256);
        }
#pragma unroll
        for (int n = 0; n < 4; ++n) {
            b_h[n] = *(const bf16x8*)(smem + 16384 + bco + n * 256);
            b_l[n] = *(const bf16x8*)(smem + 24576 + bco + n * 256);
        }
#pragma unroll
        for (int m = 0; m < 4; ++m)
#pragma unroll
            for (int n = 0; n < 4; ++n) {
                acc[m][n] = __builtin_amdgcn_mfma_f32_16x16x32_bf16(a_h[m], b_h[n], acc[m][n], 0, 0, 0);
                acc[m][n] = __builtin_amdgcn_mfma_f32_16x16x32_bf16(a_h[m], b_l[n], acc[m][n], 0, 0, 0);
                acc[m][n] = __builtin_amdgcn_mfma_f32_16x16x32_bf16(a_l[m], b_h[n], acc[m][n], 0, 0, 0);
            }
        __syncthreads();
    }
    // epilogue: C[row][col] = acc + bias  (C/D map: col=lane&15, row=(lane>>4)*4+reg)
#pragma unroll
    for (int n = 0; n < 4; ++n) {
        int col = colBase + wn * 64 + n * 16 + (lane & 15);
        float bv = bias1[col] + (bias2 ? bias2[col] : 0.f);
#pragma unroll
        for (int m = 0; m < 4; ++m) {
            int row0 = rowBase + wm * 64 + m * 16 + (lane >> 4) * 4;
#pragma unroll
            for (int r = 0; r < 4; ++r)
                C[(size_t)(row0 + r) * ldc + col] = acc[m][n][r] + bv;
        }
    }
}

// ---------------- BatchNorm ----------------
__global__ void bn_partial(const float* __restrict__ h, float* __restrict__ pS, float* __restrict__ pS2) {
    int col = blockIdx.x * 256 + threadIdx.x;
    int chunk = blockIdx.y;
    if (col >= H) return;
    const float* p = h + (size_t)chunk * 256 * NP + col;
    float s = 0.f, s2 = 0.f;
    for (int r = 0; r < 256; ++r) {
        float v = p[(size_t)r * NP];
        s += v; s2 += v * v;
    }
    pS[chunk * H + col] = s;
    pS2[chunk * H + col] = s2;
}

__global__ void bn_final(const float* __restrict__ pS, const float* __restrict__ pS2,
                         const float* __restrict__ gamma, const float* __restrict__ beta,
                         float* __restrict__ bnA, float* __restrict__ bnB) {
    int c = blockIdx.x * 256 + threadIdx.x;
    if (c >= NP) return;
    if (c >= H) { bnA[c] = 0.f; bnB[c] = 0.f; return; }
    float s = 0.f, s2 = 0.f;
    for (int j = 0; j < 32; ++j) { s += pS[j * H + c]; s2 += pS2[j * H + c]; }
    float mean = s * (1.f / NROWS);
    float var = s2 * (1.f / NROWS) - mean * mean;
    float inv = rsqrtf(var + EPSBN);
    float a = gamma[c] * inv;
    bnA[c] = a;
    bnB[c] = beta[c] - mean * a;
}

// BN apply + lrelu + bf16 hi/lo split, 4 cols/thread
__global__ void bn_apply_split(const float* __restrict__ h, const float* __restrict__ bnA,
                               const float* __restrict__ bnB,
                               unsigned short* __restrict__ oh, unsigned short* __restrict__ ol) {
    int i = blockIdx.x * 256 + threadIdx.x;
    if (i >= NROWS * (NP / 4)) return;
    int r = i / (NP / 4), c4 = (i - r * (NP / 4)) * 4;
    const float4 v = *(const float4*)(h + (size_t)r * NP + c4);
    const float4 a = *(const float4*)(bnA + c4);
    const float4 b = *(const float4*)(bnB + c4);
    float x[4] = {lrelu(a.x * v.x + b.x), lrelu(a.y * v.y + b.y),
                  lrelu(a.z * v.z + b.z), lrelu(a.w * v.w + b.w)};
    ushort4 hi, lo;
    unsigned short h0 = f2bf(x[0]), h1 = f2bf(x[1]), h2 = f2bf(x[2]), h3 = f2bf(x[3]);
    hi = make_ushort4(h0, h1, h2, h3);
    lo = make_ushort4(f2bf(x[0] - bf2f(h0)), f2bf(x[1] - bf2f(h1)),
                      f2bf(x[2] - bf2f(h2)), f2bf(x[3] - bf2f(h3)));
    *(ushort4*)(oh + (size_t)r * NP + c4) = hi;
    *(ushort4*)(ol + (size_t)r * NP + c4) = lo;
}

// ---------------- softmax + loss ----------------
__global__ __launch_bounds__(256) void softmax_loss(
    const float* __restrict__ y, float* __restrict__ ysoft,
    const unsigned char* __restrict__ sl, float* __restrict__ lossacc, int addloss) {
    int i = blockIdx.x * 256 + threadIdx.x;
    int r = i / 5, p = i - r * 5;
    const float* yr = y + (size_t)r * OCP + p;
    float m = -1e30f;
#pragma unroll
    for (int c = 0; c < 26; ++c) m = fmaxf(m, yr[c * 5]);
    float e[26];
    float s = 0.f;
#pragma unroll
    for (int c = 0; c < 26; ++c) { e[c] = expf(yr[c * 5] - m); s += e[c]; }
    float inv = 1.f / s;
#pragma unroll
    for (int c = 0; c < 26; ++c) ysoft[(size_t)r * OC + c * 5 + p] = e[c] * inv;
    float contrib = 0.f;
    if (addloss) {
        int letter = sl[r * 8 + p];
        contrib = logf(s) + m - yr[letter * 5];
    }
    __shared__ float red[256];
    red[threadIdx.x] = contrib;
    __syncthreads();
    for (int off = 128; off > 0; off >>= 1) {
        if (threadIdx.x < off) red[threadIdx.x] += red[threadIdx.x + off];
        __syncthreads();
    }
    if (threadIdx.x == 0 && addloss) atomicAdd(lossacc, red[0] * (1.f / (NROWS * 5)));
}

// ---------------- argmax over vocabulary ----------------
__global__ __launch_bounds__(64) void argmax_kernel(const float* __restrict__ ysoft,
                                                    const unsigned char* __restrict__ gl,
                                                    int* __restrict__ idxbuf) {
    int r = blockIdx.x;
    __shared__ float row[OC];
    int tid = threadIdx.x;
    for (int j = tid; j < OC; j += 64) row[j] = ysoft[(size_t)r * OC + j];
    __syncthreads();
    float best = -1e30f;
    int bi = NG;
    for (int g = tid; g < NG; g += 64) {
        const unsigned char* q = gl + g * 8;
        float s = row[q[0] * 5 + 0] + row[q[1] * 5 + 1] + row[q[2] * 5 + 2] +
                  row[q[3] * 5 + 3] + row[q[4] * 5 + 4];
        if (s > best) { best = s; bi = g; }
    }
    for (int off = 32; off > 0; off >>= 1) {
        float ob = __shfl_down(best, off);
        int oi = __shfl_down(bi, off);
        if (ob > best || (ob == best && oi < bi)) { best = ob; bi = oi; }
    }
    if (tid == 0) idxbuf[r] = bi;
}

// ---------------- hint update / scores ----------------
__global__ void hints_update(const int* __restrict__ idxbuf, const unsigned char* __restrict__ gl,
                             const unsigned char* __restrict__ sl, const unsigned int* __restrict__ msk,
                             unsigned short* __restrict__ hXh, float* __restrict__ scores,
                             int* __restrict__ solvedf, const float* __restrict__ gm,
                             float* __restrict__ dout, int turn) {
    int r = blockIdx.x * 256 + threadIdx.x;
    if (r >= NROWS) return;
    int w = idxbuf[r];
    const unsigned char* q = gl + w * 8;
    const unsigned char* s = sl + r * 8;
    unsigned int mk = msk[r];
    unsigned short* hrow = hXh + (size_t)r * KX;
    int allg = 1;
#pragma unroll
    for (int p = 0; p < 5; ++p) {
        int g = q[p];
        int off;
        if (g == s[p]) {
            off = g * 5 + p;  // green
        } else {
            allg = 0;
            off = ((mk >> g) & 1u) ? (130 + g * 5 + p) : (260 + g);  // yellow : black
        }
        hrow[off] = f2bf(bf2f(hrow[off]) + 1.f);
    }
    solvedf[r] = allg;
    if (allg && scores[r] > (float)(turn + 1)) scores[r] = (float)(turn + 1);
    if (turn == 0 && r == 0) {
        for (int j = 0; j < OC; ++j) dout[3 + j] = gm[(size_t)w * OC + j];
    }
}

__global__ void final_reduce(const float* __restrict__ scores, const int* __restrict__ solvedf,
                             const float* __restrict__ lossacc, float* __restrict__ dout) {
    __shared__ float rs[256];
    __shared__ int ri[256];
    int tid = threadIdx.x;
    float s = 0.f;
    int c = 0;
    for (int r = tid; r < NROWS; r += 256) { s += scores[r]; c += solvedf[r]; }
    rs[tid] = s; ri[tid] = c;
    __syncthreads();
    for (int off = 128; off > 0; off >>= 1) {
        if (tid < off) { rs[tid] += rs[tid + off]; ri[tid] += ri[tid + off]; }
        __syncthreads();
    }
    if (tid == 0) {
        dout[0] = lossacc[0];
        dout[1] = rs[0];
        dout[2] = (float)ri[0];
    }
}

// ---------------- launch ----------------
extern "C" void kernel_launch(void* const* d_in, const int* in_sizes, int n_in,
                              void* d_out, int out_size, void* d_ws, size_t ws_size,
                              hipStream_t stream) {
    const float* sols   = (const float*)d_in[0];
    const float* gm     = (const float*)d_in[1];
    const float* W0     = (const float*)d_in[2];
    const float* b0     = (const float*)d_in[3];
    const float* gammas = (const float*)d_in[4];
    const float* betas  = (const float*)d_in[5];
    const float* Wh     = (const float*)d_in[6];
    const float* bh     = (const float*)d_in[7];
    const float* Wout   = (const float*)d_in[8];
    const float* bout   = (const float*)d_in[9];
    float* dout = (float*)d_out;

    char* p = (char*)d_ws;
    auto alloc = [&](size_t bytes) { void* r = (void*)p; p += (bytes + 255) & ~(size_t)255; return r; };
    unsigned short* hXh = (unsigned short*)alloc((size_t)NROWS * KX * 2);
    unsigned short* hXl = (unsigned short*)alloc((size_t)NROWS * KX * 2);
    unsigned short* hAh = (unsigned short*)alloc((size_t)NROWS * NP * 2);
    unsigned short* hAl = (unsigned short*)alloc((size_t)NROWS * NP * 2);
    float* hraw  = (float*)alloc((size_t)NROWS * NP * 4);
    float* ybuf  = hraw;                                   // alias: hraw dead when ybuf written
    float* ysoft = hraw + (size_t)NROWS * OCP;             // fits inside hraw after ybuf
    unsigned short* B0Th  = (unsigned short*)alloc((size_t)NP * KX * 2);
    unsigned short* B0Tl  = (unsigned short*)alloc((size_t)NP * KX * 2);
    unsigned short* WhTh  = (unsigned short*)alloc((size_t)3 * NP * NP * 2);
    unsigned short* WhTl  = (unsigned short*)alloc((size_t)3 * NP * NP * 2);
    unsigned short* BoTh  = (unsigned short*)alloc((size_t)OCP * NP * 2);
    unsigned short* BoTl  = (unsigned short*)alloc((size_t)OCP * NP * 2);
    float* b0p   = (float*)alloc(NP * 4);
    float* w0t   = (float*)alloc(6 * NP * 4);
    float* bhp   = (float*)alloc(3 * NP * 4);
    float* boutp = (float*)alloc(OCP * 4);
    float* pS    = (float*)alloc((size_t)32 * H * 4);
    float* pS2   = (float*)alloc((size_t)32 * H * 4);
    float* bnA   = (float*)alloc(NP * 4);
    float* bnB   = (float*)alloc(NP * 4);
    float* scores  = (float*)alloc(NROWS * 4);
    float* lossacc = (float*)alloc(256);
    int* solvedf = (int*)alloc(NROWS * 4);
    int* idxbuf  = (int*)alloc(NROWS * 4);
    unsigned char* gl = (unsigned char*)alloc(NG * 8);
    unsigned char* sl = (unsigned char*)alloc(NROWS * 8);
    unsigned int* msk = (unsigned int*)alloc(NROWS * 4);

    // ---- prep ----
    transpose_split<<<dim3(KX / 32, NP / 32), dim3(32, 8), 0, stream>>>(W0, 286, H, H, B0Th, B0Tl, KX, NP);
    for (int l = 0; l < 3; ++l)
        transpose_split<<<dim3(NP / 32, NP / 32), dim3(32, 8), 0, stream>>>(
            Wh + (size_t)l * H * H, H, H, H, WhTh + (size_t)l * NP * NP, WhTl + (size_t)l * NP * NP, NP, NP);
    transpose_split<<<dim3(NP / 32, OCP / 32), dim3(32, 8), 0, stream>>>(Wout, H, OC, OC, BoTh, BoTl, NP, OCP);
    prep_bias<<<41, 256, 0, stream>>>(W0, b0, bh, bout, b0p, w0t, bhp, boutp);
    prep_guess_letters<<<(NG + 255) / 256, 256, 0, stream>>>(gm, gl);
    prep_sol_letters<<<(NROWS + 255) / 256, 256, 0, stream>>>(sols, sl, msk);
    init_state<<<(NROWS * KX + 255) / 256, 256, 0, stream>>>(hXh, hXl, scores, solvedf, lossacc);

    for (int t = 0; t < 6; ++t) {
        // h = X @ W0 + b0 + W0[286+t]  (turn one-hot folded into bias2)
        gemm_bf16x2<<<dim3(NROWS / 128, NP / 128), 256, 0, stream>>>(
            hXh, hXl, KX, B0Th, B0Tl, KX, hraw, NP, b0p, w0t + t * NP, KX / 32);
        for (int l = 0; l < 4; ++l) {
            bn_partial<<<dim3(4, 32), 256, 0, stream>>>(hraw, pS, pS2);
            bn_final<<<4, 256, 0, stream>>>(pS, pS2, gammas + (size_t)l * H, betas + (size_t)l * H, bnA, bnB);
            bn_apply_split<<<(NROWS * (NP / 4) + 255) / 256, 256, 0, stream>>>(hraw, bnA, bnB, hAh, hAl);
            if (l < 3) {
                gemm_bf16x2<<<dim3(NROWS / 128, NP / 128), 256, 0, stream>>>(
                    hAh, hAl, NP, WhTh + (size_t)l * NP * NP, WhTl + (size_t)l * NP * NP, NP,
                    hraw, NP, bhp + l * NP, nullptr, NP / 32);
            } else {
                gemm_bf16x2<<<dim3(NROWS / 128, OCP / 128), 256, 0, stream>>>(
                    hAh, hAl, NP, BoTh, BoTl, NP, ybuf, OCP, boutp, nullptr, NP / 32);
            }
        }
        softmax_loss<<<(NROWS * 5) / 256, 256, 0, stream>>>(ybuf, ysoft, sl, lossacc, (t >= 1) ? 1 : 0);
        argmax_kernel<<<NROWS, 64, 0, stream>>>(ysoft, gl, idxbuf);
        hints_update<<<(NROWS + 255) / 256, 256, 0, stream>>>(idxbuf, gl, sl, msk, hXh, scores,
                                                              solvedf, gm, dout, t);
    }
    final_reduce<<<1, 256, 0, stream>>>(scores, solvedf, lossacc, dout);
}

// Round 3
// 2738.434 us; speedup vs baseline: 2.8421x; 1.1394x over previous
//
#include <hip/hip_runtime.h>

#define NROWS 8192
#define NG    12972
#define H     1000
#define NP    1024   // padded hidden width
#define KX    288    // padded hints width (multiple of 32)
#define OCP   256    // padded output cols
#define OC    130
#define EPSBN 1e-5f
#define MBLK  (NROWS / 128)   // 64 row-blocks => 64 stat partials

typedef __attribute__((ext_vector_type(8))) short bf16x8;
typedef __attribute__((ext_vector_type(4))) float f32x4;

__device__ __forceinline__ float lrelu(float x) { return x >= 0.f ? x : 0.2f * x; }
__device__ __forceinline__ unsigned short f2bf(float f) {
    unsigned u = __float_as_uint(f);
    return (unsigned short)((u + 0x7fffu + ((u >> 16) & 1u)) >> 16);
}
__device__ __forceinline__ float bf2f(unsigned short h) {
    return __uint_as_float(((unsigned)h) << 16);
}

// ---------------- prep: transpose + split fp32 -> bf16 hi/lo, B^T layout ----------------
__global__ void transpose_split(const float* __restrict__ src, int R, int C, int srcStride,
                                unsigned short* __restrict__ dhi, unsigned short* __restrict__ dlo,
                                int Rp, int Cp) {
    __shared__ float tile[32][33];
    int k0 = blockIdx.x * 32;
    int n0 = blockIdx.y * 32;
    int tx = threadIdx.x, ty = threadIdx.y;  // 32 x 8
#pragma unroll
    for (int i = 0; i < 32; i += 8) {
        int k = k0 + ty + i, n = n0 + tx;
        tile[ty + i][tx] = (k < R && n < C) ? src[(size_t)k * srcStride + n] : 0.f;
    }
    __syncthreads();
#pragma unroll
    for (int i = 0; i < 32; i += 8) {
        int n = n0 + ty + i, k = k0 + tx;
        if (n < Cp && k < Rp) {
            float v = tile[tx][ty + i];
            unsigned short hi = f2bf(v);
            dhi[(size_t)n * Rp + k] = hi;
            dlo[(size_t)n * Rp + k] = f2bf(v - bf2f(hi));
        }
    }
}

__global__ void prep_bias(const float* __restrict__ W0, const float* __restrict__ b0,
                          const float* __restrict__ bh, const float* __restrict__ bout,
                          float* __restrict__ b0p, float* __restrict__ w0t,
                          float* __restrict__ bhp, float* __restrict__ boutp) {
    int i = blockIdx.x * 256 + threadIdx.x;
    if (i < 1024) { b0p[i] = (i < H) ? b0[i] : 0.f; return; }
    i -= 1024;
    if (i < 6 * 1024) {
        int t = i >> 10, n = i & 1023;
        w0t[i] = (n < H) ? W0[(size_t)(286 + t) * H + n] : 0.f;
        return;
    }
    i -= 6 * 1024;
    if (i < 3 * 1024) {
        int l = i >> 10, n = i & 1023;
        bhp[i] = (n < H) ? bh[l * H + n] : 0.f;
        return;
    }
    i -= 3 * 1024;
    if (i < OCP) { boutp[i] = (i < OC) ? bout[i] : 0.f; }
}

// gl: letters (for hint update). glp: packed softmax offsets letter*5+p (5 bytes in uint2).
__global__ void prep_guess_letters(const float* __restrict__ gm, unsigned char* __restrict__ gl,
                                   uint2* __restrict__ glp) {
    int g = blockIdx.x * blockDim.x + threadIdx.x;
    if (g >= NG) return;
    unsigned off[5];
    for (int p = 0; p < 5; ++p) {
        int letter = 0;
        for (int c = 0; c < 26; ++c)
            if (gm[(size_t)g * 130 + c * 5 + p] > 0.5f) { letter = c; break; }
        gl[g * 8 + p] = (unsigned char)letter;
        off[p] = (unsigned)(letter * 5 + p);
    }
    gl[g * 8 + 5] = gl[g * 8 + 6] = gl[g * 8 + 7] = 0;
    glp[g] = make_uint2(off[0] | (off[1] << 8) | (off[2] << 16) | (off[3] << 24), off[4]);
}

__global__ void prep_sol_letters(const float* __restrict__ sols, unsigned char* __restrict__ sl,
                                 unsigned int* __restrict__ msk) {
    int r = blockIdx.x * blockDim.x + threadIdx.x;
    if (r >= NROWS) return;
    unsigned int m = 0;
    for (int p = 0; p < 5; ++p) {
        int letter = 0;
        for (int c = 0; c < 26; ++c)
            if (sols[(size_t)r * 130 + c * 5 + p] > 0.5f) { letter = c; break; }
        sl[r * 8 + p] = (unsigned char)letter;
        m |= 1u << letter;
    }
    sl[r * 8 + 5] = sl[r * 8 + 6] = sl[r * 8 + 7] = 0;
    msk[r] = m;
}

__global__ void init_state(unsigned short* __restrict__ hXh, unsigned short* __restrict__ hXl,
                           float* __restrict__ scores, int* __restrict__ solvedf,
                           float* __restrict__ lossacc) {
    int i = blockIdx.x * blockDim.x + threadIdx.x;
    if (i < NROWS * KX) { hXh[i] = 0; hXl[i] = 0; }
    if (i < NROWS) { scores[i] = 7.f; solvedf[i] = 0; }
    if (i == 0) lossacc[0] = 0.f;
}

// ---------------- GEMM: C = Ah*Bh + Ah*Bl + Al*Bh (+bias), fused column stats ----------------
// Block 128x128, 4 waves (2x2), BK=32. LDS: Ah|Al|Bh|Bl tiles, 32KB.
// If pS != nullptr: also writes per-block column partial sums of C (incl. bias) to
// pS/pS2[blockIdx.x * NP + col] — deterministic (each (bx,by) owns a distinct slice).
__global__ __launch_bounds__(256, 2) void gemm_bf16x2(
    const unsigned short* __restrict__ Ah, const unsigned short* __restrict__ Al, int lda,
    const unsigned short* __restrict__ Bh, const unsigned short* __restrict__ Bl, int ldb,
    float* __restrict__ C, int ldc,
    const float* __restrict__ bias1, const float* __restrict__ bias2, int kiter,
    float* __restrict__ pS, float* __restrict__ pS2) {
    __shared__ char smem[32768];
    const int tid = threadIdx.x;
    const int lane = tid & 63;
    const int rowBase = blockIdx.x * 128;
    const int colBase = blockIdx.y * 128;
    const int wm = (tid >> 6) & 1;
    const int wn = tid >> 7;

    const unsigned short* gsrc[8];
    int ldsuni[8];
#pragma unroll
    for (int i = 0; i < 8; ++i) {
        int c = i * 256 + tid;
        int tile = c >> 9, w = c & 511, kb = w >> 7, r = w & 127;
        const unsigned short* plane = (tile == 0) ? Ah : (tile == 1) ? Al : (tile == 2) ? Bh : Bl;
        int ld = (tile < 2) ? lda : ldb;
        int base = (tile < 2) ? rowBase : colBase;
        gsrc[i] = plane + (size_t)(base + r) * ld + kb * 8;
        ldsuni[i] = (i * 256 + (tid & ~63)) * 16;
    }

    f32x4 acc[4][4];
    const f32x4 z = {0.f, 0.f, 0.f, 0.f};
#pragma unroll
    for (int m = 0; m < 4; ++m)
#pragma unroll
        for (int n = 0; n < 4; ++n) acc[m][n] = z;

    const int aro = (lane >> 4) * 2048 + (wm * 64 + (lane & 15)) * 16;
    const int bco = (lane >> 4) * 2048 + (wn * 64 + (lane & 15)) * 16;

    for (int t = 0; t < kiter; ++t) {
#if __has_builtin(__builtin_amdgcn_global_load_lds)
#pragma unroll
        for (int i = 0; i < 8; ++i) {
            __builtin_amdgcn_global_load_lds(
                (const __attribute__((address_space(1))) void*)(gsrc[i] + t * 32),
                (__attribute__((address_space(3))) void*)(smem + ldsuni[i]), 16, 0, 0);
        }
        __syncthreads();
#else
        bf16x8 stg[8];
#pragma unroll
        for (int i = 0; i < 8; ++i) stg[i] = *(const bf16x8*)(gsrc[i] + t * 32);
        __syncthreads();
#pragma unroll
        for (int i = 0; i < 8; ++i) *(bf16x8*)(smem + (i * 256 + tid) * 16) = stg[i];
        __syncthreads();
#endif
        bf16x8 a_h[4], a_l[4], b_h[4], b_l[4];
#pragma unroll
        for (int m = 0; m < 4; ++m) {
            a_h[m] = *(const bf16x8*)(smem + aro + m * 256);
            a_l[m] = *(const bf16x8*)(smem + 8192 + aro + m * 256);
        }
#pragma unroll
        for (int n = 0; n < 4; ++n) {
            b_h[n] = *(const bf16x8*)(smem + 16384 + bco + n * 256);
            b_l[n] = *(const bf16x8*)(smem + 24576 + bco + n * 256);
        }
#pragma unroll
        for (int m = 0; m < 4; ++m)
#pragma unroll
            for (int n = 0; n < 4; ++n) {
                acc[m][n] = __builtin_amdgcn_mfma_f32_16x16x32_bf16(a_h[m], b_h[n], acc[m][n], 0, 0, 0);
                acc[m][n] = __builtin_amdgcn_mfma_f32_16x16x32_bf16(a_h[m], b_l[n], acc[m][n], 0, 0, 0);
                acc[m][n] = __builtin_amdgcn_mfma_f32_16x16x32_bf16(a_l[m], b_h[n], acc[m][n], 0, 0, 0);
            }
        __syncthreads();
    }

    // epilogue (smem contents dead; last loop iter ended with __syncthreads)
    float* sS  = (float*)smem;           // [2][128]
    float* sS2 = (float*)smem + 256;     // [2][128]
    const int lane16 = lane & 15, lanehi = lane >> 4;
#pragma unroll
    for (int n = 0; n < 4; ++n) {
        int col = colBase + wn * 64 + n * 16 + lane16;
        float bv = bias1[col] + (bias2 ? bias2[col] : 0.f);
        float s = 0.f, s2 = 0.f;
#pragma unroll
        for (int m = 0; m < 4; ++m) {
            int row0 = rowBase + wm * 64 + m * 16 + lanehi * 4;
#pragma unroll
            for (int r = 0; r < 4; ++r) {
                float cv = acc[m][n][r] + bv;
                C[(size_t)(row0 + r) * ldc + col] = cv;
                s += cv; s2 += cv * cv;
            }
        }
        if (pS) {
            s += __shfl_xor(s, 16);  s += __shfl_xor(s, 32);
            s2 += __shfl_xor(s2, 16); s2 += __shfl_xor(s2, 32);
            if (lanehi == 0) {
                int lcol = wn * 64 + n * 16 + lane16;
                sS[wm * 128 + lcol] = s;
                sS2[wm * 128 + lcol] = s2;
            }
        }
    }
    if (pS) {
        __syncthreads();
        if (tid < 128) {
            int col = colBase + tid;
            pS[(size_t)blockIdx.x * NP + col] = sS[tid] + sS[128 + tid];
            pS2[(size_t)blockIdx.x * NP + col] = sS2[tid] + sS2[128 + tid];
        }
    }
}

// ---------------- BatchNorm coefficient finalize (reduce 64 block partials) ----------------
__global__ void bn_final(const float* __restrict__ pS, const float* __restrict__ pS2,
                         const float* __restrict__ gamma, const float* __restrict__ beta,
                         float* __restrict__ bnA, float* __restrict__ bnB) {
    int c = blockIdx.x * 256 + threadIdx.x;
    if (c >= NP) return;
    if (c >= H) { bnA[c] = 0.f; bnB[c] = 0.f; return; }
    float s = 0.f, s2 = 0.f;
    for (int j = 0; j < MBLK; ++j) { s += pS[(size_t)j * NP + c]; s2 += pS2[(size_t)j * NP + c]; }
    float mean = s * (1.f / NROWS);
    float var = s2 * (1.f / NROWS) - mean * mean;
    float inv = rsqrtf(var + EPSBN);
    float a = gamma[c] * inv;
    bnA[c] = a;
    bnB[c] = beta[c] - mean * a;
}

// BN apply + lrelu + bf16 hi/lo split, 4 cols/thread
__global__ void bn_apply_split(const float* __restrict__ h, const float* __restrict__ bnA,
                               const float* __restrict__ bnB,
                               unsigned short* __restrict__ oh, unsigned short* __restrict__ ol) {
    int i = blockIdx.x * 256 + threadIdx.x;
    if (i >= NROWS * (NP / 4)) return;
    int r = i / (NP / 4), c4 = (i - r * (NP / 4)) * 4;
    const float4 v = *(const float4*)(h + (size_t)r * NP + c4);
    const float4 a = *(const float4*)(bnA + c4);
    const float4 b = *(const float4*)(bnB + c4);
    float x[4] = {lrelu(a.x * v.x + b.x), lrelu(a.y * v.y + b.y),
                  lrelu(a.z * v.z + b.z), lrelu(a.w * v.w + b.w)};
    unsigned short h0 = f2bf(x[0]), h1 = f2bf(x[1]), h2 = f2bf(x[2]), h3 = f2bf(x[3]);
    ushort4 hi = make_ushort4(h0, h1, h2, h3);
    ushort4 lo = make_ushort4(f2bf(x[0] - bf2f(h0)), f2bf(x[1] - bf2f(h1)),
                              f2bf(x[2] - bf2f(h2)), f2bf(x[3] - bf2f(h3)));
    *(ushort4*)(oh + (size_t)r * NP + c4) = hi;
    *(ushort4*)(ol + (size_t)r * NP + c4) = lo;
}

// ---------------- softmax + loss ----------------
__global__ __launch_bounds__(256) void softmax_loss(
    const float* __restrict__ y, float* __restrict__ ysoft,
    const unsigned char* __restrict__ sl, float* __restrict__ lossacc, int addloss) {
    int i = blockIdx.x * 256 + threadIdx.x;
    int r = i / 5, p = i - r * 5;
    const float* yr = y + (size_t)r * OCP + p;
    float m = -1e30f;
#pragma unroll
    for (int c = 0; c < 26; ++c) m = fmaxf(m, yr[c * 5]);
    float e[26];
    float s = 0.f;
#pragma unroll
    for (int c = 0; c < 26; ++c) { e[c] = expf(yr[c * 5] - m); s += e[c]; }
    float inv = 1.f / s;
#pragma unroll
    for (int c = 0; c < 26; ++c) ysoft[(size_t)r * OC + c * 5 + p] = e[c] * inv;
    float contrib = 0.f;
    if (addloss) {
        int letter = sl[r * 8 + p];
        contrib = logf(s) + m - yr[letter * 5];
    }
    __shared__ float red[256];
    red[threadIdx.x] = contrib;
    __syncthreads();
    for (int off = 128; off > 0; off >>= 1) {
        if (threadIdx.x < off) red[threadIdx.x] += red[threadIdx.x + off];
        __syncthreads();
    }
    if (threadIdx.x == 0 && addloss) atomicAdd(lossacc, red[0] * (1.f / (NROWS * 5)));
}

// ---------------- argmax over vocabulary (packed-offset inner loop) ----------------
__global__ __launch_bounds__(64) void argmax_kernel(const float* __restrict__ ysoft,
                                                    const uint2* __restrict__ glp,
                                                    int* __restrict__ idxbuf) {
    int r = blockIdx.x;
    __shared__ float row[132];
    int tid = threadIdx.x;
    for (int j = tid; j < OC; j += 64) row[j] = ysoft[(size_t)r * OC + j];
    __syncthreads();
    float best = -1e30f;
    int bi = 1 << 30;
    for (int g = tid; g < NG; g += 64) {
        uint2 w = glp[g];
        float s = row[w.x & 0xffu] + row[(w.x >> 8) & 0xffu] + row[(w.x >> 16) & 0xffu] +
                  row[w.x >> 24] + row[w.y & 0xffu];
        if (s > best) { best = s; bi = g; }  // strict > keeps first max within lane
    }
    for (int off = 32; off > 0; off >>= 1) {
        float ob = __shfl_down(best, off);
        int oi = __shfl_down(bi, off);
        if (ob > best || (ob == best && oi < bi)) { best = ob; bi = oi; }
    }
    if (tid == 0) idxbuf[r] = bi;
}

// ---------------- hint update / scores ----------------
__global__ void hints_update(const int* __restrict__ idxbuf, const unsigned char* __restrict__ gl,
                             const unsigned char* __restrict__ sl, const unsigned int* __restrict__ msk,
                             unsigned short* __restrict__ hXh, float* __restrict__ scores,
                             int* __restrict__ solvedf, const float* __restrict__ gm,
                             float* __restrict__ dout, int turn) {
    int r = blockIdx.x * 256 + threadIdx.x;
    if (r >= NROWS) return;
    int w = idxbuf[r];
    const unsigned char* q = gl + w * 8;
    const unsigned char* s = sl + r * 8;
    unsigned int mk = msk[r];
    unsigned short* hrow = hXh + (size_t)r * KX;
    int allg = 1;
#pragma unroll
    for (int p = 0; p < 5; ++p) {
        int g = q[p];
        int off;
        if (g == s[p]) {
            off = g * 5 + p;  // green
        } else {
            allg = 0;
            off = ((mk >> g) & 1u) ? (130 + g * 5 + p) : (260 + g);  // yellow : black
        }
        hrow[off] = f2bf(bf2f(hrow[off]) + 1.f);
    }
    solvedf[r] = allg;
    if (allg && scores[r] > (float)(turn + 1)) scores[r] = (float)(turn + 1);
    if (turn == 0 && r == 0) {
        for (int j = 0; j < OC; ++j) dout[3 + j] = gm[(size_t)w * OC + j];
    }
}

__global__ void final_reduce(const float* __restrict__ scores, const int* __restrict__ solvedf,
                             const float* __restrict__ lossacc, float* __restrict__ dout) {
    __shared__ float rs[256];
    __shared__ int ri[256];
    int tid = threadIdx.x;
    float s = 0.f;
    int c = 0;
    for (int r = tid; r < NROWS; r += 256) { s += scores[r]; c += solvedf[r]; }
    rs[tid] = s; ri[tid] = c;
    __syncthreads();
    for (int off = 128; off > 0; off >>= 1) {
        if (tid < off) { rs[tid] += rs[tid + off]; ri[tid] += ri[tid + off]; }
        __syncthreads();
    }
    if (tid == 0) {
        dout[0] = lossacc[0];
        dout[1] = rs[0];
        dout[2] = (float)ri[0];
    }
}

// ---------------- launch ----------------
extern "C" void kernel_launch(void* const* d_in, const int* in_sizes, int n_in,
                              void* d_out, int out_size, void* d_ws, size_t ws_size,
                              hipStream_t stream) {
    const float* sols   = (const float*)d_in[0];
    const float* gm     = (const float*)d_in[1];
    const float* W0     = (const float*)d_in[2];
    const float* b0     = (const float*)d_in[3];
    const float* gammas = (const float*)d_in[4];
    const float* betas  = (const float*)d_in[5];
    const float* Wh     = (const float*)d_in[6];
    const float* bh     = (const float*)d_in[7];
    const float* Wout   = (const float*)d_in[8];
    const float* bout   = (const float*)d_in[9];
    float* dout = (float*)d_out;

    char* p = (char*)d_ws;
    auto alloc = [&](size_t bytes) { void* r = (void*)p; p += (bytes + 255) & ~(size_t)255; return r; };
    unsigned short* hXh = (unsigned short*)alloc((size_t)NROWS * KX * 2);
    unsigned short* hXl = (unsigned short*)alloc((size_t)NROWS * KX * 2);
    unsigned short* hAh = (unsigned short*)alloc((size_t)NROWS * NP * 2);
    unsigned short* hAl = (unsigned short*)alloc((size_t)NROWS * NP * 2);
    float* hraw  = (float*)alloc((size_t)NROWS * NP * 4);
    float* ybuf  = hraw;
    float* ysoft = hraw + (size_t)NROWS * OCP;
    unsigned short* B0Th  = (unsigned short*)alloc((size_t)NP * KX * 2);
    unsigned short* B0Tl  = (unsigned short*)alloc((size_t)NP * KX * 2);
    unsigned short* WhTh  = (unsigned short*)alloc((size_t)3 * NP * NP * 2);
    unsigned short* WhTl  = (unsigned short*)alloc((size_t)3 * NP * NP * 2);
    unsigned short* BoTh  = (unsigned short*)alloc((size_t)OCP * NP * 2);
    unsigned short* BoTl  = (unsigned short*)alloc((size_t)OCP * NP * 2);
    float* b0p   = (float*)alloc(NP * 4);
    float* w0t   = (float*)alloc(6 * NP * 4);
    float* bhp   = (float*)alloc(3 * NP * 4);
    float* boutp = (float*)alloc(OCP * 4);
    float* pS    = (float*)alloc((size_t)MBLK * NP * 4);
    float* pS2   = (float*)alloc((size_t)MBLK * NP * 4);
    float* bnA   = (float*)alloc(NP * 4);
    float* bnB   = (float*)alloc(NP * 4);
    float* scores  = (float*)alloc(NROWS * 4);
    float* lossacc = (float*)alloc(256);
    int* solvedf = (int*)alloc(NROWS * 4);
    int* idxbuf  = (int*)alloc(NROWS * 4);
    unsigned char* gl = (unsigned char*)alloc(NG * 8);
    uint2* glp = (uint2*)alloc(NG * 8);
    unsigned char* sl = (unsigned char*)alloc(NROWS * 8);
    unsigned int* msk = (unsigned int*)alloc(NROWS * 4);

    // ---- prep ----
    transpose_split<<<dim3(KX / 32, NP / 32), dim3(32, 8), 0, stream>>>(W0, 286, H, H, B0Th, B0Tl, KX, NP);
    for (int l = 0; l < 3; ++l)
        transpose_split<<<dim3(NP / 32, NP / 32), dim3(32, 8), 0, stream>>>(
            Wh + (size_t)l * H * H, H, H, H, WhTh + (size_t)l * NP * NP, WhTl + (size_t)l * NP * NP, NP, NP);
    transpose_split<<<dim3(NP / 32, OCP / 32), dim3(32, 8), 0, stream>>>(Wout, H, OC, OC, BoTh, BoTl, NP, OCP);
    prep_bias<<<41, 256, 0, stream>>>(W0, b0, bh, bout, b0p, w0t, bhp, boutp);
    prep_guess_letters<<<(NG + 255) / 256, 256, 0, stream>>>(gm, gl, glp);
    prep_sol_letters<<<(NROWS + 255) / 256, 256, 0, stream>>>(sols, sl, msk);
    init_state<<<(NROWS * KX + 255) / 256, 256, 0, stream>>>(hXh, hXl, scores, solvedf, lossacc);

    for (int t = 0; t < 6; ++t) {
        gemm_bf16x2<<<dim3(MBLK, NP / 128), 256, 0, stream>>>(
            hXh, hXl, KX, B0Th, B0Tl, KX, hraw, NP, b0p, w0t + t * NP, KX / 32, pS, pS2);
        for (int l = 0; l < 4; ++l) {
            bn_final<<<4, 256, 0, stream>>>(pS, pS2, gammas + (size_t)l * H, betas + (size_t)l * H, bnA, bnB);
            bn_apply_split<<<(NROWS * (NP / 4) + 255) / 256, 256, 0, stream>>>(hraw, bnA, bnB, hAh, hAl);
            if (l < 3) {
                gemm_bf16x2<<<dim3(MBLK, NP / 128), 256, 0, stream>>>(
                    hAh, hAl, NP, WhTh + (size_t)l * NP * NP, WhTl + (size_t)l * NP * NP, NP,
                    hraw, NP, bhp + l * NP, nullptr, NP / 32, pS, pS2);
            } else {
                gemm_bf16x2<<<dim3(MBLK, OCP / 128), 256, 0, stream>>>(
                    hAh, hAl, NP, BoTh, BoTl, NP, ybuf, OCP, boutp, nullptr, NP / 32,
                    nullptr, nullptr);
            }
        }
        softmax_loss<<<(NROWS * 5) / 256, 256, 0, stream>>>(ybuf, ysoft, sl, lossacc, (t >= 1) ? 1 : 0);
        argmax_kernel<<<NROWS, 64, 0, stream>>>(ysoft, glp, idxbuf);
        hints_update<<<(NROWS + 255) / 256, 256, 0, stream>>>(idxbuf, gl, sl, msk, hXh, scores,
                                                              solvedf, gm, dout, t);
    }
    final_reduce<<<1, 256, 0, stream>>>(scores, solvedf, lossacc, dout);
}

// Round 4
// 2576.242 us; speedup vs baseline: 3.0210x; 1.0630x over previous
//
#include <hip/hip_runtime.h>

#define NROWS 8192
#define NG    12972
#define H     1000
#define NP    1024   // padded hidden width
#define KX    288    // padded hints width (multiple of 32)
#define OCP   256    // padded output cols
#define OC    130
#define EPSBN 1e-5f
#define MBLK  (NROWS / 128)   // 64 row-blocks => 64 stat partials

typedef __attribute__((ext_vector_type(8))) short bf16x8;
typedef __attribute__((ext_vector_type(4))) float f32x4;

__device__ __forceinline__ float lrelu(float x) { return x >= 0.f ? x : 0.2f * x; }
__device__ __forceinline__ unsigned short f2bf(float f) {
    unsigned u = __float_as_uint(f);
    return (unsigned short)((u + 0x7fffu + ((u >> 16) & 1u)) >> 16);
}
__device__ __forceinline__ float bf2f(unsigned short h) {
    return __uint_as_float(((unsigned)h) << 16);
}

// ---------------- prep: transpose + split fp32 -> bf16 hi/lo, B^T layout ----------------
__global__ void transpose_split(const float* __restrict__ src, int R, int C, int srcStride,
                                unsigned short* __restrict__ dhi, unsigned short* __restrict__ dlo,
                                int Rp, int Cp) {
    __shared__ float tile[32][33];
    int k0 = blockIdx.x * 32;
    int n0 = blockIdx.y * 32;
    int tx = threadIdx.x, ty = threadIdx.y;  // 32 x 8
#pragma unroll
    for (int i = 0; i < 32; i += 8) {
        int k = k0 + ty + i, n = n0 + tx;
        tile[ty + i][tx] = (k < R && n < C) ? src[(size_t)k * srcStride + n] : 0.f;
    }
    __syncthreads();
#pragma unroll
    for (int i = 0; i < 32; i += 8) {
        int n = n0 + ty + i, k = k0 + tx;
        if (n < Cp && k < Rp) {
            float v = tile[tx][ty + i];
            unsigned short hi = f2bf(v);
            dhi[(size_t)n * Rp + k] = hi;
            dlo[(size_t)n * Rp + k] = f2bf(v - bf2f(hi));
        }
    }
}

__global__ void prep_bias(const float* __restrict__ W0, const float* __restrict__ b0,
                          const float* __restrict__ bh, const float* __restrict__ bout,
                          float* __restrict__ b0p, float* __restrict__ w0t,
                          float* __restrict__ bhp, float* __restrict__ boutp) {
    int i = blockIdx.x * 256 + threadIdx.x;
    if (i < 1024) { b0p[i] = (i < H) ? b0[i] : 0.f; return; }
    i -= 1024;
    if (i < 6 * 1024) {
        int t = i >> 10, n = i & 1023;
        w0t[i] = (n < H) ? W0[(size_t)(286 + t) * H + n] : 0.f;
        return;
    }
    i -= 6 * 1024;
    if (i < 3 * 1024) {
        int l = i >> 10, n = i & 1023;
        bhp[i] = (n < H) ? bh[l * H + n] : 0.f;
        return;
    }
    i -= 3 * 1024;
    if (i < OCP) { boutp[i] = (i < OC) ? bout[i] : 0.f; }
}

// gl: letters (for hint update). glp: packed softmax offsets letter*5+p (5 bytes in uint2).
__global__ void prep_guess_letters(const float* __restrict__ gm, unsigned char* __restrict__ gl,
                                   uint2* __restrict__ glp) {
    int g = blockIdx.x * blockDim.x + threadIdx.x;
    if (g >= NG) return;
    unsigned off[5];
    for (int p = 0; p < 5; ++p) {
        int letter = 0;
        for (int c = 0; c < 26; ++c)
            if (gm[(size_t)g * 130 + c * 5 + p] > 0.5f) { letter = c; break; }
        gl[g * 8 + p] = (unsigned char)letter;
        off[p] = (unsigned)(letter * 5 + p);
    }
    gl[g * 8 + 5] = gl[g * 8 + 6] = gl[g * 8 + 7] = 0;
    glp[g] = make_uint2(off[0] | (off[1] << 8) | (off[2] << 16) | (off[3] << 24), off[4]);
}

__global__ void prep_sol_letters(const float* __restrict__ sols, unsigned char* __restrict__ sl,
                                 unsigned int* __restrict__ msk) {
    int r = blockIdx.x * blockDim.x + threadIdx.x;
    if (r >= NROWS) return;
    unsigned int m = 0;
    for (int p = 0; p < 5; ++p) {
        int letter = 0;
        for (int c = 0; c < 26; ++c)
            if (sols[(size_t)r * 130 + c * 5 + p] > 0.5f) { letter = c; break; }
        sl[r * 8 + p] = (unsigned char)letter;
        m |= 1u << letter;
    }
    sl[r * 8 + 5] = sl[r * 8 + 6] = sl[r * 8 + 7] = 0;
    msk[r] = m;
}

__global__ void init_state(unsigned short* __restrict__ hXh, float* __restrict__ scores,
                           int* __restrict__ solvedf, float* __restrict__ lossacc) {
    int i = blockIdx.x * blockDim.x + threadIdx.x;
    if (i < NROWS * KX) hXh[i] = 0;
    if (i < NROWS) { scores[i] = 7.f; solvedf[i] = 0; }
    if (i == 0) lossacc[0] = 0.f;
}

// ---------------- GEMM: C = Ah*Bh + Ah*Bl (+ Al*Bh) (+bias), fused column stats ----------------
// Block 128x128, 4 waves (2x2), BK=32, 2-phase double-buffered global_load_lds staging.
// HAS_AL=false: A exact in bf16 (Al==0), 2 MFMA passes, 3 LDS tiles per buffer.
template <bool HAS_AL>
__global__ __launch_bounds__(256, 2) void gemm_bf16x2(
    const unsigned short* __restrict__ Ah, const unsigned short* __restrict__ Al, int lda,
    const unsigned short* __restrict__ Bh, const unsigned short* __restrict__ Bl, int ldb,
    float* __restrict__ C, int ldc,
    const float* __restrict__ bias1, const float* __restrict__ bias2, int kiter,
    float* __restrict__ pS, float* __restrict__ pS2) {
    constexpr int NCH = HAS_AL ? 8 : 6;              // 256-thread x 16B staging chunks per K-tile
    constexpr int BUFSZ = HAS_AL ? 32768 : 24576;    // bytes per LDS buffer
    constexpr int offBh = HAS_AL ? 16384 : 8192;
    constexpr int offBl = HAS_AL ? 24576 : 16384;
    __shared__ char smem[2 * BUFSZ];
    const int tid = threadIdx.x;
    const int lane = tid & 63;
    const int rowBase = blockIdx.x * 128;
    const int colBase = blockIdx.y * 128;
    const int wm = (tid >> 6) & 1;
    const int wn = tid >> 7;

    // staging map: chunk c = i*256+tid; tile=c>>9; w=c&511; kb=w>>7; r=w&127
    const unsigned short* gsrc[NCH];
    int ldsuni[NCH];
#pragma unroll
    for (int i = 0; i < NCH; ++i) {
        int c = i * 256 + tid;
        int tile = c >> 9, w = c & 511, kb = w >> 7, r = w & 127;
        const unsigned short* plane;
        int ld, base;
        if (HAS_AL) {
            plane = (tile == 0) ? Ah : (tile == 1) ? Al : (tile == 2) ? Bh : Bl;
            ld = (tile < 2) ? lda : ldb;
            base = (tile < 2) ? rowBase : colBase;
        } else {
            plane = (tile == 0) ? Ah : (tile == 1) ? Bh : Bl;
            ld = (tile == 0) ? lda : ldb;
            base = (tile == 0) ? rowBase : colBase;
        }
        gsrc[i] = plane + (size_t)(base + r) * ld + kb * 8;
        ldsuni[i] = (i * 256 + (tid & ~63)) * 16;  // wave-uniform byte base
    }

    f32x4 acc[4][4];
    const f32x4 z = {0.f, 0.f, 0.f, 0.f};
#pragma unroll
    for (int m = 0; m < 4; ++m)
#pragma unroll
        for (int n = 0; n < 4; ++n) acc[m][n] = z;

    const int aro = (lane >> 4) * 2048 + (wm * 64 + (lane & 15)) * 16;
    const int bco = (lane >> 4) * 2048 + (wn * 64 + (lane & 15)) * 16;

    // prologue: stage K-tile 0 into buffer 0
#pragma unroll
    for (int i = 0; i < NCH; ++i)
        __builtin_amdgcn_global_load_lds(
            (const __attribute__((address_space(1))) void*)(gsrc[i]),
            (__attribute__((address_space(3))) void*)(smem + ldsuni[i]), 16, 0, 0);
    __syncthreads();

    int cur = 0;
    for (int t = 0; t < kiter; ++t) {
        // phase 1: issue next K-tile's loads into the other buffer (stay in flight across compute)
        if (t + 1 < kiter) {
            const int nb = (cur ^ 1) * BUFSZ;
#pragma unroll
            for (int i = 0; i < NCH; ++i)
                __builtin_amdgcn_global_load_lds(
                    (const __attribute__((address_space(1))) void*)(gsrc[i] + (size_t)(t + 1) * 32),
                    (__attribute__((address_space(3))) void*)(smem + nb + ldsuni[i]), 16, 0, 0);
        }
#if __has_builtin(__builtin_amdgcn_sched_barrier)
        __builtin_amdgcn_sched_barrier(0);  // keep stage-issue above ds_read/MFMA
#endif
        // phase 2: compute on current buffer
        const char* base = smem + cur * BUFSZ;
        bf16x8 a_h[4], a_l[4], b_h[4], b_l[4];
#pragma unroll
        for (int m = 0; m < 4; ++m) {
            a_h[m] = *(const bf16x8*)(base + aro + m * 256);
            if constexpr (HAS_AL) a_l[m] = *(const bf16x8*)(base + 8192 + aro + m * 256);
        }
#pragma unroll
        for (int n = 0; n < 4; ++n) {
            b_h[n] = *(const bf16x8*)(base + offBh + bco + n * 256);
            b_l[n] = *(const bf16x8*)(base + offBl + bco + n * 256);
        }
#pragma unroll
        for (int m = 0; m < 4; ++m)
#pragma unroll
            for (int n = 0; n < 4; ++n) {
                acc[m][n] = __builtin_amdgcn_mfma_f32_16x16x32_bf16(a_h[m], b_h[n], acc[m][n], 0, 0, 0);
                acc[m][n] = __builtin_amdgcn_mfma_f32_16x16x32_bf16(a_h[m], b_l[n], acc[m][n], 0, 0, 0);
                if constexpr (HAS_AL)
                    acc[m][n] = __builtin_amdgcn_mfma_f32_16x16x32_bf16(a_l[m], b_h[n], acc[m][n], 0, 0, 0);
            }
        __syncthreads();  // drains vmcnt(0): next buffer is ready; ds_reads of cur done
        cur ^= 1;
    }

    // epilogue (smem contents dead; last loop iter ended with __syncthreads)
    float* sS  = (float*)smem;           // [2][128]
    float* sS2 = (float*)smem + 256;     // [2][128]
    const int lane16 = lane & 15, lanehi = lane >> 4;
#pragma unroll
    for (int n = 0; n < 4; ++n) {
        int col = colBase + wn * 64 + n * 16 + lane16;
        float bv = bias1[col] + (bias2 ? bias2[col] : 0.f);
        float s = 0.f, s2 = 0.f;
#pragma unroll
        for (int m = 0; m < 4; ++m) {
            int row0 = rowBase + wm * 64 + m * 16 + lanehi * 4;
#pragma unroll
            for (int r = 0; r < 4; ++r) {
                float cv = acc[m][n][r] + bv;
                C[(size_t)(row0 + r) * ldc + col] = cv;
                s += cv; s2 += cv * cv;
            }
        }
        if (pS) {
            s += __shfl_xor(s, 16);  s += __shfl_xor(s, 32);
            s2 += __shfl_xor(s2, 16); s2 += __shfl_xor(s2, 32);
            if (lanehi == 0) {
                int lcol = wn * 64 + n * 16 + lane16;
                sS[wm * 128 + lcol] = s;
                sS2[wm * 128 + lcol] = s2;
            }
        }
    }
    if (pS) {
        __syncthreads();
        if (tid < 128) {
            int col = colBase + tid;
            pS[(size_t)blockIdx.x * NP + col] = sS[tid] + sS[128 + tid];
            pS2[(size_t)blockIdx.x * NP + col] = sS2[tid] + sS2[128 + tid];
        }
    }
}

// ---------------- BatchNorm coefficient finalize (reduce 64 block partials) ----------------
__global__ void bn_final(const float* __restrict__ pS, const float* __restrict__ pS2,
                         const float* __restrict__ gamma, const float* __restrict__ beta,
                         float* __restrict__ bnA, float* __restrict__ bnB) {
    int c = blockIdx.x * 256 + threadIdx.x;
    if (c >= NP) return;
    if (c >= H) { bnA[c] = 0.f; bnB[c] = 0.f; return; }
    float s = 0.f, s2 = 0.f;
    for (int j = 0; j < MBLK; ++j) { s += pS[(size_t)j * NP + c]; s2 += pS2[(size_t)j * NP + c]; }
    float mean = s * (1.f / NROWS);
    float var = s2 * (1.f / NROWS) - mean * mean;
    float inv = rsqrtf(var + EPSBN);
    float a = gamma[c] * inv;
    bnA[c] = a;
    bnB[c] = beta[c] - mean * a;
}

// BN apply + lrelu + bf16 hi/lo split, 4 cols/thread
__global__ void bn_apply_split(const float* __restrict__ h, const float* __restrict__ bnA,
                               const float* __restrict__ bnB,
                               unsigned short* __restrict__ oh, unsigned short* __restrict__ ol) {
    int i = blockIdx.x * 256 + threadIdx.x;
    if (i >= NROWS * (NP / 4)) return;
    int r = i / (NP / 4), c4 = (i - r * (NP / 4)) * 4;
    const float4 v = *(const float4*)(h + (size_t)r * NP + c4);
    const float4 a = *(const float4*)(bnA + c4);
    const float4 b = *(const float4*)(bnB + c4);
    float x[4] = {lrelu(a.x * v.x + b.x), lrelu(a.y * v.y + b.y),
                  lrelu(a.z * v.z + b.z), lrelu(a.w * v.w + b.w)};
    unsigned short h0 = f2bf(x[0]), h1 = f2bf(x[1]), h2 = f2bf(x[2]), h3 = f2bf(x[3]);
    ushort4 hi = make_ushort4(h0, h1, h2, h3);
    ushort4 lo = make_ushort4(f2bf(x[0] - bf2f(h0)), f2bf(x[1] - bf2f(h1)),
                              f2bf(x[2] - bf2f(h2)), f2bf(x[3] - bf2f(h3)));
    *(ushort4*)(oh + (size_t)r * NP + c4) = hi;
    *(ushort4*)(ol + (size_t)r * NP + c4) = lo;
}

// ---------------- softmax + loss ----------------
__global__ __launch_bounds__(256) void softmax_loss(
    const float* __restrict__ y, float* __restrict__ ysoft,
    const unsigned char* __restrict__ sl, float* __restrict__ lossacc, int addloss) {
    int i = blockIdx.x * 256 + threadIdx.x;
    int r = i / 5, p = i - r * 5;
    const float* yr = y + (size_t)r * OCP + p;
    float m = -1e30f;
#pragma unroll
    for (int c = 0; c < 26; ++c) m = fmaxf(m, yr[c * 5]);
    float e[26];
    float s = 0.f;
#pragma unroll
    for (int c = 0; c < 26; ++c) { e[c] = expf(yr[c * 5] - m); s += e[c]; }
    float inv = 1.f / s;
#pragma unroll
    for (int c = 0; c < 26; ++c) ysoft[(size_t)r * OC + c * 5 + p] = e[c] * inv;
    float contrib = 0.f;
    if (addloss) {
        int letter = sl[r * 8 + p];
        contrib = logf(s) + m - yr[letter * 5];
    }
    __shared__ float red[256];
    red[threadIdx.x] = contrib;
    __syncthreads();
    for (int off = 128; off > 0; off >>= 1) {
        if (threadIdx.x < off) red[threadIdx.x] += red[threadIdx.x + off];
        __syncthreads();
    }
    if (threadIdx.x == 0 && addloss) atomicAdd(lossacc, red[0] * (1.f / (NROWS * 5)));
}

// ---------------- argmax over vocabulary: 4 rows/block, float4-packed LDS ----------------
__global__ __launch_bounds__(256) void argmax_kernel(const float* __restrict__ ysoft,
                                                     const uint2* __restrict__ glp,
                                                     int* __restrict__ idxbuf) {
    const int r0 = blockIdx.x * 4;
    __shared__ float4 pk[130];           // pk[c] = {row0[c], row1[c], row2[c], row3[c]}
    __shared__ float wb[4][4];
    __shared__ int wi[4][4];
    const int tid = threadIdx.x;
    for (int j = tid; j < 520; j += 256)
        ((float*)pk)[j] = ysoft[(size_t)(r0 + (j & 3)) * OC + (j >> 2)];
    __syncthreads();

    float b0 = -1e30f, b1 = -1e30f, b2 = -1e30f, b3 = -1e30f;
    int i0 = 1 << 30, i1 = 1 << 30, i2 = 1 << 30, i3 = 1 << 30;
    for (int g = tid; g < NG; g += 256) {
        uint2 w = glp[g];
        float4 s0 = pk[w.x & 255];
        float4 s1 = pk[(w.x >> 8) & 255];
        float4 s2 = pk[(w.x >> 16) & 255];
        float4 s3 = pk[w.x >> 24];
        float4 s4 = pk[w.y & 255];
        // same left-assoc add order as reference gather: ((((o0+o1)+o2)+o3)+o4)
        float vx = s0.x + s1.x; vx += s2.x; vx += s3.x; vx += s4.x;
        float vy = s0.y + s1.y; vy += s2.y; vy += s3.y; vy += s4.y;
        float vz = s0.z + s1.z; vz += s2.z; vz += s3.z; vz += s4.z;
        float vw = s0.w + s1.w; vw += s2.w; vw += s3.w; vw += s4.w;
        if (vx > b0) { b0 = vx; i0 = g; }
        if (vy > b1) { b1 = vy; i1 = g; }
        if (vz > b2) { b2 = vz; i2 = g; }
        if (vw > b3) { b3 = vw; i3 = g; }
    }
    // wave butterfly reduce (value desc, index asc on ties)
#pragma unroll
    for (int off = 1; off < 64; off <<= 1) {
        float o; int oi;
        o = __shfl_xor(b0, off); oi = __shfl_xor(i0, off);
        if (o > b0 || (o == b0 && oi < i0)) { b0 = o; i0 = oi; }
        o = __shfl_xor(b1, off); oi = __shfl_xor(i1, off);
        if (o > b1 || (o == b1 && oi < i1)) { b1 = o; i1 = oi; }
        o = __shfl_xor(b2, off); oi = __shfl_xor(i2, off);
        if (o > b2 || (o == b2 && oi < i2)) { b2 = o; i2 = oi; }
        o = __shfl_xor(b3, off); oi = __shfl_xor(i3, off);
        if (o > b3 || (o == b3 && oi < i3)) { b3 = o; i3 = oi; }
    }
    const int wid = tid >> 6, lane = tid & 63;
    if (lane == 0) {
        wb[wid][0] = b0; wi[wid][0] = i0;
        wb[wid][1] = b1; wi[wid][1] = i1;
        wb[wid][2] = b2; wi[wid][2] = i2;
        wb[wid][3] = b3; wi[wid][3] = i3;
    }
    __syncthreads();
    if (tid < 4) {
        float b = wb[0][tid]; int x = wi[0][tid];
#pragma unroll
        for (int wv = 1; wv < 4; ++wv)
            if (wb[wv][tid] > b || (wb[wv][tid] == b && wi[wv][tid] < x)) { b = wb[wv][tid]; x = wi[wv][tid]; }
        idxbuf[r0 + tid] = x;
    }
}

// ---------------- hint update / scores ----------------
__global__ void hints_update(const int* __restrict__ idxbuf, const unsigned char* __restrict__ gl,
                             const unsigned char* __restrict__ sl, const unsigned int* __restrict__ msk,
                             unsigned short* __restrict__ hXh, float* __restrict__ scores,
                             int* __restrict__ solvedf, const float* __restrict__ gm,
                             float* __restrict__ dout, int turn) {
    int r = blockIdx.x * 256 + threadIdx.x;
    if (r >= NROWS) return;
    int w = idxbuf[r];
    const unsigned char* q = gl + w * 8;
    const unsigned char* s = sl + r * 8;
    unsigned int mk = msk[r];
    unsigned short* hrow = hXh + (size_t)r * KX;
    int allg = 1;
#pragma unroll
    for (int p = 0; p < 5; ++p) {
        int g = q[p];
        int off;
        if (g == s[p]) {
            off = g * 5 + p;  // green
        } else {
            allg = 0;
            off = ((mk >> g) & 1u) ? (130 + g * 5 + p) : (260 + g);  // yellow : black
        }
        hrow[off] = f2bf(bf2f(hrow[off]) + 1.f);
    }
    solvedf[r] = allg;
    if (allg && scores[r] > (float)(turn + 1)) scores[r] = (float)(turn + 1);
    if (turn == 0 && r == 0) {
        for (int j = 0; j < OC; ++j) dout[3 + j] = gm[(size_t)w * OC + j];
    }
}

__global__ void final_reduce(const float* __restrict__ scores, const int* __restrict__ solvedf,
                             const float* __restrict__ lossacc, float* __restrict__ dout) {
    __shared__ float rs[256];
    __shared__ int ri[256];
    int tid = threadIdx.x;
    float s = 0.f;
    int c = 0;
    for (int r = tid; r < NROWS; r += 256) { s += scores[r]; c += solvedf[r]; }
    rs[tid] = s; ri[tid] = c;
    __syncthreads();
    for (int off = 128; off > 0; off >>= 1) {
        if (tid < off) { rs[tid] += rs[tid + off]; ri[tid] += ri[tid + off]; }
        __syncthreads();
    }
    if (tid == 0) {
        dout[0] = lossacc[0];
        dout[1] = rs[0];
        dout[2] = (float)ri[0];
    }
}

// ---------------- launch ----------------
extern "C" void kernel_launch(void* const* d_in, const int* in_sizes, int n_in,
                              void* d_out, int out_size, void* d_ws, size_t ws_size,
                              hipStream_t stream) {
    const float* sols   = (const float*)d_in[0];
    const float* gm     = (const float*)d_in[1];
    const float* W0     = (const float*)d_in[2];
    const float* b0     = (const float*)d_in[3];
    const float* gammas = (const float*)d_in[4];
    const float* betas  = (const float*)d_in[5];
    const float* Wh     = (const float*)d_in[6];
    const float* bh     = (const float*)d_in[7];
    const float* Wout   = (const float*)d_in[8];
    const float* bout   = (const float*)d_in[9];
    float* dout = (float*)d_out;

    char* p = (char*)d_ws;
    auto alloc = [&](size_t bytes) { void* r = (void*)p; p += (bytes + 255) & ~(size_t)255; return r; };
    unsigned short* hXh = (unsigned short*)alloc((size_t)NROWS * KX * 2);
    unsigned short* hAh = (unsigned short*)alloc((size_t)NROWS * NP * 2);
    unsigned short* hAl = (unsigned short*)alloc((size_t)NROWS * NP * 2);
    float* hraw  = (float*)alloc((size_t)NROWS * NP * 4);
    float* ybuf  = hraw;
    float* ysoft = hraw + (size_t)NROWS * OCP;
    unsigned short* B0Th  = (unsigned short*)alloc((size_t)NP * KX * 2);
    unsigned short* B0Tl  = (unsigned short*)alloc((size_t)NP * KX * 2);
    unsigned short* WhTh  = (unsigned short*)alloc((size_t)3 * NP * NP * 2);
    unsigned short* WhTl  = (unsigned short*)alloc((size_t)3 * NP * NP * 2);
    unsigned short* BoTh  = (unsigned short*)alloc((size_t)OCP * NP * 2);
    unsigned short* BoTl  = (unsigned short*)alloc((size_t)OCP * NP * 2);
    float* b0p   = (float*)alloc(NP * 4);
    float* w0t   = (float*)alloc(6 * NP * 4);
    float* bhp   = (float*)alloc(3 * NP * 4);
    float* boutp = (float*)alloc(OCP * 4);
    float* pS    = (float*)alloc((size_t)MBLK * NP * 4);
    float* pS2   = (float*)alloc((size_t)MBLK * NP * 4);
    float* bnA   = (float*)alloc(NP * 4);
    float* bnB   = (float*)alloc(NP * 4);
    float* scores  = (float*)alloc(NROWS * 4);
    float* lossacc = (float*)alloc(256);
    int* solvedf = (int*)alloc(NROWS * 4);
    int* idxbuf  = (int*)alloc(NROWS * 4);
    unsigned char* gl = (unsigned char*)alloc(NG * 8);
    uint2* glp = (uint2*)alloc(NG * 8);
    unsigned char* sl = (unsigned char*)alloc(NROWS * 8);
    unsigned int* msk = (unsigned int*)alloc(NROWS * 4);

    // ---- prep ----
    transpose_split<<<dim3(KX / 32, NP / 32), dim3(32, 8), 0, stream>>>(W0, 286, H, H, B0Th, B0Tl, KX, NP);
    for (int l = 0; l < 3; ++l)
        transpose_split<<<dim3(NP / 32, NP / 32), dim3(32, 8), 0, stream>>>(
            Wh + (size_t)l * H * H, H, H, H, WhTh + (size_t)l * NP * NP, WhTl + (size_t)l * NP * NP, NP, NP);
    transpose_split<<<dim3(NP / 32, OCP / 32), dim3(32, 8), 0, stream>>>(Wout, H, OC, OC, BoTh, BoTl, NP, OCP);
    prep_bias<<<41, 256, 0, stream>>>(W0, b0, bh, bout, b0p, w0t, bhp, boutp);
    prep_guess_letters<<<(NG + 255) / 256, 256, 0, stream>>>(gm, gl, glp);
    prep_sol_letters<<<(NROWS + 255) / 256, 256, 0, stream>>>(sols, sl, msk);
    init_state<<<(NROWS * KX + 255) / 256, 256, 0, stream>>>(hXh, scores, solvedf, lossacc);

    for (int t = 0; t < 6; ++t) {
        // h = X @ W0 + b0 + W0[286+t]  (hints exact in bf16 -> 2-pass GEMM)
        gemm_bf16x2<false><<<dim3(MBLK, NP / 128), 256, 0, stream>>>(
            hXh, nullptr, KX, B0Th, B0Tl, KX, hraw, NP, b0p, w0t + t * NP, KX / 32, pS, pS2);
        for (int l = 0; l < 4; ++l) {
            bn_final<<<4, 256, 0, stream>>>(pS, pS2, gammas + (size_t)l * H, betas + (size_t)l * H, bnA, bnB);
            bn_apply_split<<<(NROWS * (NP / 4) + 255) / 256, 256, 0, stream>>>(hraw, bnA, bnB, hAh, hAl);
            if (l < 3) {
                gemm_bf16x2<true><<<dim3(MBLK, NP / 128), 256, 0, stream>>>(
                    hAh, hAl, NP, WhTh + (size_t)l * NP * NP, WhTl + (size_t)l * NP * NP, NP,
                    hraw, NP, bhp + l * NP, nullptr, NP / 32, pS, pS2);
            } else {
                gemm_bf16x2<true><<<dim3(MBLK, OCP / 128), 256, 0, stream>>>(
                    hAh, hAl, NP, BoTh, BoTl, NP, ybuf, OCP, boutp, nullptr, NP / 32,
                    nullptr, nullptr);
            }
        }
        softmax_loss<<<(NROWS * 5) / 256, 256, 0, stream>>>(ybuf, ysoft, sl, lossacc, (t >= 1) ? 1 : 0);
        argmax_kernel<<<NROWS / 4, 256, 0, stream>>>(ysoft, glp, idxbuf);
        hints_update<<<(NROWS + 255) / 256, 256, 0, stream>>>(idxbuf, gl, sl, msk, hXh, scores,
                                                              solvedf, gm, dout, t);
    }
    final_reduce<<<1, 256, 0, stream>>>(scores, solvedf, lossacc, dout);
}

// Round 5
// 2473.206 us; speedup vs baseline: 3.1469x; 1.0417x over previous
//
#include <hip/hip_runtime.h>

#define NROWS 8192
#define NG    12972
#define H     1000
#define NP    1024   // padded hidden width
#define KX    288    // padded hints width (multiple of 32)
#define OCP   256    // padded output cols
#define OC    130
#define EPSBN 1e-5f
#define MBLK  (NROWS / 128)   // 64 row-blocks => 64 stat partials

typedef __attribute__((ext_vector_type(8))) short bf16x8;
typedef __attribute__((ext_vector_type(4))) float f32x4;

__device__ __forceinline__ float lrelu(float x) { return x >= 0.f ? x : 0.2f * x; }
__device__ __forceinline__ unsigned short f2bf(float f) {
    unsigned u = __float_as_uint(f);
    return (unsigned short)((u + 0x7fffu + ((u >> 16) & 1u)) >> 16);
}
__device__ __forceinline__ float bf2f(unsigned short h) {
    return __uint_as_float(((unsigned)h) << 16);
}

// ---------------- prep: transpose + split fp32 -> bf16 hi/lo, B^T layout ----------------
__global__ void transpose_split(const float* __restrict__ src, int R, int C, int srcStride,
                                unsigned short* __restrict__ dhi, unsigned short* __restrict__ dlo,
                                int Rp, int Cp) {
    __shared__ float tile[32][33];
    int k0 = blockIdx.x * 32;
    int n0 = blockIdx.y * 32;
    int tx = threadIdx.x, ty = threadIdx.y;  // 32 x 8
#pragma unroll
    for (int i = 0; i < 32; i += 8) {
        int k = k0 + ty + i, n = n0 + tx;
        tile[ty + i][tx] = (k < R && n < C) ? src[(size_t)k * srcStride + n] : 0.f;
    }
    __syncthreads();
#pragma unroll
    for (int i = 0; i < 32; i += 8) {
        int n = n0 + ty + i, k = k0 + tx;
        if (n < Cp && k < Rp) {
            float v = tile[tx][ty + i];
            unsigned short hi = f2bf(v);
            dhi[(size_t)n * Rp + k] = hi;
            dlo[(size_t)n * Rp + k] = f2bf(v - bf2f(hi));
        }
    }
}

__global__ void prep_bias(const float* __restrict__ W0, const float* __restrict__ b0,
                          const float* __restrict__ bh, const float* __restrict__ bout,
                          float* __restrict__ b0p, float* __restrict__ w0t,
                          float* __restrict__ bhp, float* __restrict__ boutp) {
    int i = blockIdx.x * 256 + threadIdx.x;
    if (i < 1024) { b0p[i] = (i < H) ? b0[i] : 0.f; return; }
    i -= 1024;
    if (i < 6 * 1024) {
        int t = i >> 10, n = i & 1023;
        w0t[i] = (n < H) ? W0[(size_t)(286 + t) * H + n] : 0.f;
        return;
    }
    i -= 6 * 1024;
    if (i < 3 * 1024) {
        int l = i >> 10, n = i & 1023;
        bhp[i] = (n < H) ? bh[l * H + n] : 0.f;
        return;
    }
    i -= 3 * 1024;
    if (i < OCP) { boutp[i] = (i < OC) ? bout[i] : 0.f; }
}

// gl: letters (for hint update). glp: packed softmax offsets letter*5+p (5 bytes in uint2).
__global__ void prep_guess_letters(const float* __restrict__ gm, unsigned char* __restrict__ gl,
                                   uint2* __restrict__ glp) {
    int g = blockIdx.x * blockDim.x + threadIdx.x;
    if (g >= NG) return;
    unsigned off[5];
    for (int p = 0; p < 5; ++p) {
        int letter = 0;
        for (int c = 0; c < 26; ++c)
            if (gm[(size_t)g * 130 + c * 5 + p] > 0.5f) { letter = c; break; }
        gl[g * 8 + p] = (unsigned char)letter;
        off[p] = (unsigned)(letter * 5 + p);
    }
    gl[g * 8 + 5] = gl[g * 8 + 6] = gl[g * 8 + 7] = 0;
    glp[g] = make_uint2(off[0] | (off[1] << 8) | (off[2] << 16) | (off[3] << 24), off[4]);
}

__global__ void prep_sol_letters(const float* __restrict__ sols, unsigned char* __restrict__ sl,
                                 unsigned int* __restrict__ msk) {
    int r = blockIdx.x * blockDim.x + threadIdx.x;
    if (r >= NROWS) return;
    unsigned int m = 0;
    for (int p = 0; p < 5; ++p) {
        int letter = 0;
        for (int c = 0; c < 26; ++c)
            if (sols[(size_t)r * 130 + c * 5 + p] > 0.5f) { letter = c; break; }
        sl[r * 8 + p] = (unsigned char)letter;
        m |= 1u << letter;
    }
    sl[r * 8 + 5] = sl[r * 8 + 6] = sl[r * 8 + 7] = 0;
    msk[r] = m;
}

__global__ void init_state(unsigned short* __restrict__ hXh, float* __restrict__ scores,
                           int* __restrict__ solvedf, float* __restrict__ lossacc) {
    int i = blockIdx.x * blockDim.x + threadIdx.x;
    if (i < NROWS * KX) hXh[i] = 0;
    if (i < NROWS) { scores[i] = 7.f; solvedf[i] = 0; }
    if (i == 0) lossacc[0] = 0.f;
}

// ---------------- GEMM: C = Ah*Bh + Ah*Bl (+ Al*Bh) (+bias), fused column stats ----------------
// Block 128x128, 4 waves (2x2), BK=32, depth-2 pipeline with COUNTED vmcnt (T4):
//   per K-step: vmcnt(NCH) -> barrier -> ds_read -> lgkmcnt(0) -> barrier ->
//               issue T(t+2) into just-read buffer -> setprio(1) MFMA setprio(0)
// Loads stay in flight across barriers; no vmcnt(0) drain in the main loop.
template <bool HAS_AL>
__global__ __launch_bounds__(256, 2) void gemm_bf16x2(
    const unsigned short* __restrict__ Ah, const unsigned short* __restrict__ Al, int lda,
    const unsigned short* __restrict__ Bh, const unsigned short* __restrict__ Bl, int ldb,
    float* __restrict__ C, int ldc,
    const float* __restrict__ bias1, const float* __restrict__ bias2, int kiter,
    float* __restrict__ pS, float* __restrict__ pS2) {
    constexpr int NCH = HAS_AL ? 8 : 6;              // 256-thread x 16B staging chunks per K-tile
    constexpr int BUFSZ = HAS_AL ? 32768 : 24576;    // bytes per LDS buffer
    constexpr int offBh = HAS_AL ? 16384 : 8192;
    constexpr int offBl = HAS_AL ? 24576 : 16384;
    __shared__ char smem[2 * BUFSZ];
    const int tid = threadIdx.x;
    const int lane = tid & 63;
    const int rowBase = blockIdx.x * 128;
    const int colBase = blockIdx.y * 128;
    const int wm = (tid >> 6) & 1;
    const int wn = tid >> 7;

    // staging map: chunk c = i*256+tid; tile=c>>9; w=c&511; kb=w>>7; r=w&127
    const unsigned short* gsrc[NCH];
    int ldsuni[NCH];
#pragma unroll
    for (int i = 0; i < NCH; ++i) {
        int c = i * 256 + tid;
        int tile = c >> 9, w = c & 511, kb = w >> 7, r = w & 127;
        const unsigned short* plane;
        int ld, base;
        if (HAS_AL) {
            plane = (tile == 0) ? Ah : (tile == 1) ? Al : (tile == 2) ? Bh : Bl;
            ld = (tile < 2) ? lda : ldb;
            base = (tile < 2) ? rowBase : colBase;
        } else {
            plane = (tile == 0) ? Ah : (tile == 1) ? Bh : Bl;
            ld = (tile == 0) ? lda : ldb;
            base = (tile == 0) ? rowBase : colBase;
        }
        gsrc[i] = plane + (size_t)(base + r) * ld + kb * 8;
        ldsuni[i] = (i * 256 + (tid & ~63)) * 16;  // wave-uniform byte base
    }

    f32x4 acc[4][4];
    const f32x4 z = {0.f, 0.f, 0.f, 0.f};
#pragma unroll
    for (int m = 0; m < 4; ++m)
#pragma unroll
        for (int n = 0; n < 4; ++n) acc[m][n] = z;

    const int aro = (lane >> 4) * 2048 + (wm * 64 + (lane & 15)) * 16;
    const int bco = (lane >> 4) * 2048 + (wn * 64 + (lane & 15)) * 16;

    // prologue: stage T0 -> buf0, T1 -> buf1
#pragma unroll
    for (int i = 0; i < NCH; ++i)
        __builtin_amdgcn_global_load_lds(
            (const __attribute__((address_space(1))) void*)(gsrc[i]),
            (__attribute__((address_space(3))) void*)(smem + ldsuni[i]), 16, 0, 0);
    if (kiter > 1) {
#pragma unroll
        for (int i = 0; i < NCH; ++i)
            __builtin_amdgcn_global_load_lds(
                (const __attribute__((address_space(1))) void*)(gsrc[i] + 32),
                (__attribute__((address_space(3))) void*)(smem + BUFSZ + ldsuni[i]), 16, 0, 0);
    }

    for (int t = 0; t < kiter; ++t) {
        // wait: current tile landed (its NCH loads are the oldest in this wave's queue)
        if (t + 1 < kiter) {
            asm volatile("s_waitcnt vmcnt(%0)" :: "i"(NCH) : "memory");
        } else {
            asm volatile("s_waitcnt vmcnt(0)" ::: "memory");
        }
        __builtin_amdgcn_s_barrier();   // all waves' current-tile loads complete

        const char* base = smem + (t & 1) * BUFSZ;
        bf16x8 a_h[4], a_l[4], b_h[4], b_l[4];
#pragma unroll
        for (int m = 0; m < 4; ++m) {
            a_h[m] = *(const bf16x8*)(base + aro + m * 256);
            if constexpr (HAS_AL) a_l[m] = *(const bf16x8*)(base + 8192 + aro + m * 256);
        }
#pragma unroll
        for (int n = 0; n < 4; ++n) {
            b_h[n] = *(const bf16x8*)(base + offBh + bco + n * 256);
            b_l[n] = *(const bf16x8*)(base + offBl + bco + n * 256);
        }
        asm volatile("s_waitcnt lgkmcnt(0)" ::: "memory");  // my reads of buf done
        __builtin_amdgcn_s_barrier();   // ALL waves done reading buf -> safe to overwrite

        if (t + 2 < kiter) {
            const int nb = (t & 1) * BUFSZ;  // overwrite the buffer just read
#pragma unroll
            for (int i = 0; i < NCH; ++i)
                __builtin_amdgcn_global_load_lds(
                    (const __attribute__((address_space(1))) void*)(gsrc[i] + (size_t)(t + 2) * 32),
                    (__attribute__((address_space(3))) void*)(smem + nb + ldsuni[i]), 16, 0, 0);
        }
#if __has_builtin(__builtin_amdgcn_sched_barrier)
        __builtin_amdgcn_sched_barrier(0);  // pin: stage-issue above MFMA cluster
#endif
        __builtin_amdgcn_s_setprio(1);
#pragma unroll
        for (int m = 0; m < 4; ++m)
#pragma unroll
            for (int n = 0; n < 4; ++n) {
                acc[m][n] = __builtin_amdgcn_mfma_f32_16x16x32_bf16(a_h[m], b_h[n], acc[m][n], 0, 0, 0);
                acc[m][n] = __builtin_amdgcn_mfma_f32_16x16x32_bf16(a_h[m], b_l[n], acc[m][n], 0, 0, 0);
                if constexpr (HAS_AL)
                    acc[m][n] = __builtin_amdgcn_mfma_f32_16x16x32_bf16(a_l[m], b_h[n], acc[m][n], 0, 0, 0);
            }
        __builtin_amdgcn_s_setprio(0);
    }
    __syncthreads();  // protect smem reuse by epilogue stats

    // epilogue
    float* sS  = (float*)smem;           // [2][128]
    float* sS2 = (float*)smem + 256;     // [2][128]
    const int lane16 = lane & 15, lanehi = lane >> 4;
#pragma unroll
    for (int n = 0; n < 4; ++n) {
        int col = colBase + wn * 64 + n * 16 + lane16;
        float bv = bias1[col] + (bias2 ? bias2[col] : 0.f);
        float s = 0.f, s2 = 0.f;
#pragma unroll
        for (int m = 0; m < 4; ++m) {
            int row0 = rowBase + wm * 64 + m * 16 + lanehi * 4;
#pragma unroll
            for (int r = 0; r < 4; ++r) {
                float cv = acc[m][n][r] + bv;
                C[(size_t)(row0 + r) * ldc + col] = cv;
                s += cv; s2 += cv * cv;
            }
        }
        if (pS) {
            s += __shfl_xor(s, 16);  s += __shfl_xor(s, 32);
            s2 += __shfl_xor(s2, 16); s2 += __shfl_xor(s2, 32);
            if (lanehi == 0) {
                int lcol = wn * 64 + n * 16 + lane16;
                sS[wm * 128 + lcol] = s;
                sS2[wm * 128 + lcol] = s2;
            }
        }
    }
    if (pS) {
        __syncthreads();
        if (tid < 128) {
            int col = colBase + tid;
            pS[(size_t)blockIdx.x * NP + col] = sS[tid] + sS[128 + tid];
            pS2[(size_t)blockIdx.x * NP + col] = sS2[tid] + sS2[128 + tid];
        }
    }
}

// ---------------- BatchNorm coefficient finalize (reduce 64 block partials) ----------------
__global__ void bn_final(const float* __restrict__ pS, const float* __restrict__ pS2,
                         const float* __restrict__ gamma, const float* __restrict__ beta,
                         float* __restrict__ bnA, float* __restrict__ bnB) {
    int c = blockIdx.x * 256 + threadIdx.x;
    if (c >= NP) return;
    if (c >= H) { bnA[c] = 0.f; bnB[c] = 0.f; return; }
    float s = 0.f, s2 = 0.f;
    for (int j = 0; j < MBLK; ++j) { s += pS[(size_t)j * NP + c]; s2 += pS2[(size_t)j * NP + c]; }
    float mean = s * (1.f / NROWS);
    float var = s2 * (1.f / NROWS) - mean * mean;
    float inv = rsqrtf(var + EPSBN);
    float a = gamma[c] * inv;
    bnA[c] = a;
    bnB[c] = beta[c] - mean * a;
}

// BN apply + lrelu + bf16 hi/lo split, 4 cols/thread
__global__ void bn_apply_split(const float* __restrict__ h, const float* __restrict__ bnA,
                               const float* __restrict__ bnB,
                               unsigned short* __restrict__ oh, unsigned short* __restrict__ ol) {
    int i = blockIdx.x * 256 + threadIdx.x;
    if (i >= NROWS * (NP / 4)) return;
    int r = i / (NP / 4), c4 = (i - r * (NP / 4)) * 4;
    const float4 v = *(const float4*)(h + (size_t)r * NP + c4);
    const float4 a = *(const float4*)(bnA + c4);
    const float4 b = *(const float4*)(bnB + c4);
    float x[4] = {lrelu(a.x * v.x + b.x), lrelu(a.y * v.y + b.y),
                  lrelu(a.z * v.z + b.z), lrelu(a.w * v.w + b.w)};
    unsigned short h0 = f2bf(x[0]), h1 = f2bf(x[1]), h2 = f2bf(x[2]), h3 = f2bf(x[3]);
    ushort4 hi = make_ushort4(h0, h1, h2, h3);
    ushort4 lo = make_ushort4(f2bf(x[0] - bf2f(h0)), f2bf(x[1] - bf2f(h1)),
                              f2bf(x[2] - bf2f(h2)), f2bf(x[3] - bf2f(h3)));
    *(ushort4*)(oh + (size_t)r * NP + c4) = hi;
    *(ushort4*)(ol + (size_t)r * NP + c4) = lo;
}

// ---------------- softmax + loss ----------------
__global__ __launch_bounds__(256) void softmax_loss(
    const float* __restrict__ y, float* __restrict__ ysoft,
    const unsigned char* __restrict__ sl, float* __restrict__ lossacc, int addloss) {
    int i = blockIdx.x * 256 + threadIdx.x;
    int r = i / 5, p = i - r * 5;
    const float* yr = y + (size_t)r * OCP + p;
    float m = -1e30f;
#pragma unroll
    for (int c = 0; c < 26; ++c) m = fmaxf(m, yr[c * 5]);
    float e[26];
    float s = 0.f;
#pragma unroll
    for (int c = 0; c < 26; ++c) { e[c] = expf(yr[c * 5] - m); s += e[c]; }
    float inv = 1.f / s;
#pragma unroll
    for (int c = 0; c < 26; ++c) ysoft[(size_t)r * OC + c * 5 + p] = e[c] * inv;
    float contrib = 0.f;
    if (addloss) {
        int letter = sl[r * 8 + p];
        contrib = logf(s) + m - yr[letter * 5];
    }
    __shared__ float red[256];
    red[threadIdx.x] = contrib;
    __syncthreads();
    for (int off = 128; off > 0; off >>= 1) {
        if (threadIdx.x < off) red[threadIdx.x] += red[threadIdx.x + off];
        __syncthreads();
    }
    if (threadIdx.x == 0 && addloss) atomicAdd(lossacc, red[0] * (1.f / (NROWS * 5)));
}

// ---------------- argmax over vocabulary: 4 rows/block, float4-packed LDS ----------------
__global__ __launch_bounds__(256) void argmax_kernel(const float* __restrict__ ysoft,
                                                     const uint2* __restrict__ glp,
                                                     int* __restrict__ idxbuf) {
    const int r0 = blockIdx.x * 4;
    __shared__ float4 pk[130];           // pk[c] = {row0[c], row1[c], row2[c], row3[c]}
    __shared__ float wb[4][4];
    __shared__ int wi[4][4];
    const int tid = threadIdx.x;
    for (int j = tid; j < 520; j += 256)
        ((float*)pk)[j] = ysoft[(size_t)(r0 + (j & 3)) * OC + (j >> 2)];
    __syncthreads();

    float b0 = -1e30f, b1 = -1e30f, b2 = -1e30f, b3 = -1e30f;
    int i0 = 1 << 30, i1 = 1 << 30, i2 = 1 << 30, i3 = 1 << 30;
    for (int g = tid; g < NG; g += 256) {
        uint2 w = glp[g];
        float4 s0 = pk[w.x & 255];
        float4 s1 = pk[(w.x >> 8) & 255];
        float4 s2 = pk[(w.x >> 16) & 255];
        float4 s3 = pk[w.x >> 24];
        float4 s4 = pk[w.y & 255];
        float vx = s0.x + s1.x; vx += s2.x; vx += s3.x; vx += s4.x;
        float vy = s0.y + s1.y; vy += s2.y; vy += s3.y; vy += s4.y;
        float vz = s0.z + s1.z; vz += s2.z; vz += s3.z; vz += s4.z;
        float vw = s0.w + s1.w; vw += s2.w; vw += s3.w; vw += s4.w;
        if (vx > b0) { b0 = vx; i0 = g; }
        if (vy > b1) { b1 = vy; i1 = g; }
        if (vz > b2) { b2 = vz; i2 = g; }
        if (vw > b3) { b3 = vw; i3 = g; }
    }
#pragma unroll
    for (int off = 1; off < 64; off <<= 1) {
        float o; int oi;
        o = __shfl_xor(b0, off); oi = __shfl_xor(i0, off);
        if (o > b0 || (o == b0 && oi < i0)) { b0 = o; i0 = oi; }
        o = __shfl_xor(b1, off); oi = __shfl_xor(i1, off);
        if (o > b1 || (o == b1 && oi < i1)) { b1 = o; i1 = oi; }
        o = __shfl_xor(b2, off); oi = __shfl_xor(i2, off);
        if (o > b2 || (o == b2 && oi < i2)) { b2 = o; i2 = oi; }
        o = __shfl_xor(b3, off); oi = __shfl_xor(i3, off);
        if (o > b3 || (o == b3 && oi < i3)) { b3 = o; i3 = oi; }
    }
    const int wid = tid >> 6, lane = tid & 63;
    if (lane == 0) {
        wb[wid][0] = b0; wi[wid][0] = i0;
        wb[wid][1] = b1; wi[wid][1] = i1;
        wb[wid][2] = b2; wi[wid][2] = i2;
        wb[wid][3] = b3; wi[wid][3] = i3;
    }
    __syncthreads();
    if (tid < 4) {
        float b = wb[0][tid]; int x = wi[0][tid];
#pragma unroll
        for (int wv = 1; wv < 4; ++wv)
            if (wb[wv][tid] > b || (wb[wv][tid] == b && wi[wv][tid] < x)) { b = wb[wv][tid]; x = wi[wv][tid]; }
        idxbuf[r0 + tid] = x;
    }
}

// ---------------- hint update / scores ----------------
__global__ void hints_update(const int* __restrict__ idxbuf, const unsigned char* __restrict__ gl,
                             const unsigned char* __restrict__ sl, const unsigned int* __restrict__ msk,
                             unsigned short* __restrict__ hXh, float* __restrict__ scores,
                             int* __restrict__ solvedf, const float* __restrict__ gm,
                             float* __restrict__ dout, int turn) {
    int r = blockIdx.x * 256 + threadIdx.x;
    if (r >= NROWS) return;
    int w = idxbuf[r];
    const unsigned char* q = gl + w * 8;
    const unsigned char* s = sl + r * 8;
    unsigned int mk = msk[r];
    unsigned short* hrow = hXh + (size_t)r * KX;
    int allg = 1;
#pragma unroll
    for (int p = 0; p < 5; ++p) {
        int g = q[p];
        int off;
        if (g == s[p]) {
            off = g * 5 + p;  // green
        } else {
            allg = 0;
            off = ((mk >> g) & 1u) ? (130 + g * 5 + p) : (260 + g);  // yellow : black
        }
        hrow[off] = f2bf(bf2f(hrow[off]) + 1.f);
    }
    solvedf[r] = allg;
    if (allg && scores[r] > (float)(turn + 1)) scores[r] = (float)(turn + 1);
    if (turn == 0 && r == 0) {
        for (int j = 0; j < OC; ++j) dout[3 + j] = gm[(size_t)w * OC + j];
    }
}

__global__ void final_reduce(const float* __restrict__ scores, const int* __restrict__ solvedf,
                             const float* __restrict__ lossacc, float* __restrict__ dout) {
    __shared__ float rs[256];
    __shared__ int ri[256];
    int tid = threadIdx.x;
    float s = 0.f;
    int c = 0;
    for (int r = tid; r < NROWS; r += 256) { s += scores[r]; c += solvedf[r]; }
    rs[tid] = s; ri[tid] = c;
    __syncthreads();
    for (int off = 128; off > 0; off >>= 1) {
        if (tid < off) { rs[tid] += rs[tid + off]; ri[tid] += ri[tid + off]; }
        __syncthreads();
    }
    if (tid == 0) {
        dout[0] = lossacc[0];
        dout[1] = rs[0];
        dout[2] = (float)ri[0];
    }
}

// ---------------- launch ----------------
extern "C" void kernel_launch(void* const* d_in, const int* in_sizes, int n_in,
                              void* d_out, int out_size, void* d_ws, size_t ws_size,
                              hipStream_t stream) {
    const float* sols   = (const float*)d_in[0];
    const float* gm     = (const float*)d_in[1];
    const float* W0     = (const float*)d_in[2];
    const float* b0     = (const float*)d_in[3];
    const float* gammas = (const float*)d_in[4];
    const float* betas  = (const float*)d_in[5];
    const float* Wh     = (const float*)d_in[6];
    const float* bh     = (const float*)d_in[7];
    const float* Wout   = (const float*)d_in[8];
    const float* bout   = (const float*)d_in[9];
    float* dout = (float*)d_out;

    char* p = (char*)d_ws;
    auto alloc = [&](size_t bytes) { void* r = (void*)p; p += (bytes + 255) & ~(size_t)255; return r; };
    unsigned short* hXh = (unsigned short*)alloc((size_t)NROWS * KX * 2);
    unsigned short* hAh = (unsigned short*)alloc((size_t)NROWS * NP * 2);
    unsigned short* hAl = (unsigned short*)alloc((size_t)NROWS * NP * 2);
    float* hraw  = (float*)alloc((size_t)NROWS * NP * 4);
    float* ybuf  = hraw;
    float* ysoft = hraw + (size_t)NROWS * OCP;
    unsigned short* B0Th  = (unsigned short*)alloc((size_t)NP * KX * 2);
    unsigned short* B0Tl  = (unsigned short*)alloc((size_t)NP * KX * 2);
    unsigned short* WhTh  = (unsigned short*)alloc((size_t)3 * NP * NP * 2);
    unsigned short* WhTl  = (unsigned short*)alloc((size_t)3 * NP * NP * 2);
    unsigned short* BoTh  = (unsigned short*)alloc((size_t)OCP * NP * 2);
    unsigned short* BoTl  = (unsigned short*)alloc((size_t)OCP * NP * 2);
    float* b0p   = (float*)alloc(NP * 4);
    float* w0t   = (float*)alloc(6 * NP * 4);
    float* bhp   = (float*)alloc(3 * NP * 4);
    float* boutp = (float*)alloc(OCP * 4);
    float* pS    = (float*)alloc((size_t)MBLK * NP * 4);
    float* pS2   = (float*)alloc((size_t)MBLK * NP * 4);
    float* bnA   = (float*)alloc(NP * 4);
    float* bnB   = (float*)alloc(NP * 4);
    float* scores  = (float*)alloc(NROWS * 4);
    float* lossacc = (float*)alloc(256);
    int* solvedf = (int*)alloc(NROWS * 4);
    int* idxbuf  = (int*)alloc(NROWS * 4);
    unsigned char* gl = (unsigned char*)alloc(NG * 8);
    uint2* glp = (uint2*)alloc(NG * 8);
    unsigned char* sl = (unsigned char*)alloc(NROWS * 8);
    unsigned int* msk = (unsigned int*)alloc(NROWS * 4);

    // ---- prep ----
    transpose_split<<<dim3(KX / 32, NP / 32), dim3(32, 8), 0, stream>>>(W0, 286, H, H, B0Th, B0Tl, KX, NP);
    for (int l = 0; l < 3; ++l)
        transpose_split<<<dim3(NP / 32, NP / 32), dim3(32, 8), 0, stream>>>(
            Wh + (size_t)l * H * H, H, H, H, WhTh + (size_t)l * NP * NP, WhTl + (size_t)l * NP * NP, NP, NP);
    transpose_split<<<dim3(NP / 32, OCP / 32), dim3(32, 8), 0, stream>>>(Wout, H, OC, OC, BoTh, BoTl, NP, OCP);
    prep_bias<<<41, 256, 0, stream>>>(W0, b0, bh, bout, b0p, w0t, bhp, boutp);
    prep_guess_letters<<<(NG + 255) / 256, 256, 0, stream>>>(gm, gl, glp);
    prep_sol_letters<<<(NROWS + 255) / 256, 256, 0, stream>>>(sols, sl, msk);
    init_state<<<(NROWS * KX + 255) / 256, 256, 0, stream>>>(hXh, scores, solvedf, lossacc);

    for (int t = 0; t < 6; ++t) {
        // h = X @ W0 + b0 + W0[286+t]  (hints exact in bf16 -> 2-pass GEMM)
        gemm_bf16x2<false><<<dim3(MBLK, NP / 128), 256, 0, stream>>>(
            hXh, nullptr, KX, B0Th, B0Tl, KX, hraw, NP, b0p, w0t + t * NP, KX / 32, pS, pS2);
        for (int l = 0; l < 4; ++l) {
            bn_final<<<4, 256, 0, stream>>>(pS, pS2, gammas + (size_t)l * H, betas + (size_t)l * H, bnA, bnB);
            bn_apply_split<<<(NROWS * (NP / 4) + 255) / 256, 256, 0, stream>>>(hraw, bnA, bnB, hAh, hAl);
            if (l < 3) {
                gemm_bf16x2<true><<<dim3(MBLK, NP / 128), 256, 0, stream>>>(
                    hAh, hAl, NP, WhTh + (size_t)l * NP * NP, WhTl + (size_t)l * NP * NP, NP,
                    hraw, NP, bhp + l * NP, nullptr, NP / 32, pS, pS2);
            } else {
                gemm_bf16x2<true><<<dim3(MBLK, OCP / 128), 256, 0, stream>>>(
                    hAh, hAl, NP, BoTh, BoTl, NP, ybuf, OCP, boutp, nullptr, NP / 32,
                    nullptr, nullptr);
            }
        }
        softmax_loss<<<(NROWS * 5) / 256, 256, 0, stream>>>(ybuf, ysoft, sl, lossacc, (t >= 1) ? 1 : 0);
        argmax_kernel<<<NROWS / 4, 256, 0, stream>>>(ysoft, glp, idxbuf);
        hints_update<<<(NROWS + 255) / 256, 256, 0, stream>>>(idxbuf, gl, sl, msk, hXh, scores,
                                                              solvedf, gm, dout, t);
    }
    final_reduce<<<1, 256, 0, stream>>>(scores, solvedf, lossacc, dout);
}